// Round 1
// baseline (463.228 us; speedup 1.0000x reference)
//
#include <hip/hip_runtime.h>
#include <hip/hip_bf16.h>

#define DI __device__ __forceinline__

typedef __attribute__((ext_vector_type(8))) short short8;
typedef __attribute__((ext_vector_type(4))) short short4v;
typedef __attribute__((ext_vector_type(4))) float f32x4;

// RNE float -> bf16 (bit trick; inputs are finite)
DI short f2bf(float f) {
  unsigned u = __builtin_bit_cast(unsigned, f);
  unsigned r = u + 0x7fffu + ((u >> 16) & 1u);
  return (short)(r >> 16);
}

// ---------------------------------------------------------------------------
// Weight conversion: 4 x [1024x1024] fp32 -> bf16 (contiguous in ws)
// ---------------------------------------------------------------------------
__global__ __launch_bounds__(256) void convert_w(
    const float* __restrict__ wq, const float* __restrict__ wk,
    const float* __restrict__ wv, const float* __restrict__ wo,
    short* __restrict__ dst) {
  int z = blockIdx.z;
  const float* src = (z == 0) ? wq : (z == 1) ? wk : (z == 2) ? wv : wo;
  short* d = dst + (size_t)z * 1024 * 1024;
  int i = (blockIdx.x * 256 + threadIdx.x) * 4;
  float4 f = *(const float4*)(src + i);
  short4v v;
  v[0] = f2bf(f.x); v[1] = f2bf(f.y); v[2] = f2bf(f.z); v[3] = f2bf(f.w);
  *(short4v*)(d + i) = v;
}

// ---------------------------------------------------------------------------
// GEMM: C[m][n] = sum_k A[m][k] * B[n][k]   (A: [8192][1024], B: [1024][1024])
// 128x128 tile, BK=64, 4 waves x (64x64), mfma 16x16x32 bf16, XOR-swizzled LDS
// A_FP32: A is fp32 (convert during staging). OUT_HEAD: write bf16 to
// [B,H,S,Dh] layout with scale; else fp32 row-major.
// ---------------------------------------------------------------------------
template <bool A_FP32, bool OUT_HEAD>
DI void gemm_body(const void* __restrict__ Ap, const short* __restrict__ Bp,
                  void* __restrict__ Cp, float scale) {
  __shared__ __align__(16) short sA[128 * 64];
  __shared__ __align__(16) short sB[128 * 64];

  const int tid = threadIdx.x;
  const int lane = tid & 63;
  const int wid = tid >> 6;
  const int wm = wid >> 1, wn = wid & 1;
  const int bm = blockIdx.y * 128, bn = blockIdx.x * 128;
  const int l15 = lane & 15, lq = lane >> 4;

  f32x4 acc[4][4] = {};

  for (int k0 = 0; k0 < 1024; k0 += 64) {
    // ---- stage A tile (128 rows x 64 k) ----
    if (A_FP32) {
      const float* A = (const float*)Ap;
#pragma unroll
      for (int t = 0; t < 4; ++t) {
        int c = tid + t * 256;
        int row = c >> 3, col = (c & 7) * 8;
        const float* src = A + (size_t)(bm + row) * 1024 + k0 + col;
        float4 f0 = *(const float4*)src;
        float4 f1 = *(const float4*)(src + 4);
        short8 vv;
        vv[0] = f2bf(f0.x); vv[1] = f2bf(f0.y); vv[2] = f2bf(f0.z); vv[3] = f2bf(f0.w);
        vv[4] = f2bf(f1.x); vv[5] = f2bf(f1.y); vv[6] = f2bf(f1.z); vv[7] = f2bf(f1.w);
        int off = (row * 128 + col * 2) ^ ((row & 7) << 4);
        *(short8*)((char*)sA + off) = vv;
      }
    } else {
      const short* A = (const short*)Ap;
#pragma unroll
      for (int t = 0; t < 4; ++t) {
        int c = tid + t * 256;
        int row = c >> 3, col = (c & 7) * 8;
        short8 vv = *(const short8*)(A + (size_t)(bm + row) * 1024 + k0 + col);
        int off = (row * 128 + col * 2) ^ ((row & 7) << 4);
        *(short8*)((char*)sA + off) = vv;
      }
    }
    // ---- stage B tile (128 rows x 64 k) ----
#pragma unroll
    for (int t = 0; t < 4; ++t) {
      int c = tid + t * 256;
      int row = c >> 3, col = (c & 7) * 8;
      short8 vv = *(const short8*)(Bp + (size_t)(bn + row) * 1024 + k0 + col);
      int off = (row * 128 + col * 2) ^ ((row & 7) << 4);
      *(short8*)((char*)sB + off) = vv;
    }
    __syncthreads();

#pragma unroll
    for (int ks = 0; ks < 2; ++ks) {
      short8 a[4], b[4];
#pragma unroll
      for (int mt = 0; mt < 4; ++mt) {
        int row = wm * 64 + mt * 16 + l15;
        int off = (row * 128 + ks * 64 + lq * 16) ^ ((row & 7) << 4);
        a[mt] = *(const short8*)((const char*)sA + off);
      }
#pragma unroll
      for (int nt = 0; nt < 4; ++nt) {
        int row = wn * 64 + nt * 16 + l15;
        int off = (row * 128 + ks * 64 + lq * 16) ^ ((row & 7) << 4);
        b[nt] = *(const short8*)((const char*)sB + off);
      }
#pragma unroll
      for (int mt = 0; mt < 4; ++mt)
#pragma unroll
        for (int nt = 0; nt < 4; ++nt)
          acc[mt][nt] = __builtin_amdgcn_mfma_f32_16x16x32_bf16(
              a[mt], b[nt], acc[mt][nt], 0, 0, 0);
    }
    __syncthreads();
  }

  // ---- epilogue ----
#pragma unroll
  for (int mt = 0; mt < 4; ++mt) {
#pragma unroll
    for (int nt = 0; nt < 4; ++nt) {
#pragma unroll
      for (int r = 0; r < 4; ++r) {
        int rowg = bm + wm * 64 + mt * 16 + lq * 4 + r;
        int colg = bn + wn * 64 + nt * 16 + l15;
        float val = acc[mt][nt][r] * scale;
        if (OUT_HEAD) {
          int b = rowg >> 11, s = rowg & 2047;
          int h = colg >> 6, dh = colg & 63;
          ((short*)Cp)[((size_t)(b * 16 + h) * 2048 + s) * 64 + dh] = f2bf(val);
        } else {
          ((float*)Cp)[(size_t)rowg * 1024 + colg] = val;
        }
      }
    }
  }
}

__global__ __launch_bounds__(256) void proj_gemm(
    const float* __restrict__ q, const float* __restrict__ k,
    const float* __restrict__ v, const short* __restrict__ wq,
    const short* __restrict__ wk, const short* __restrict__ wv,
    short* __restrict__ xq, short* __restrict__ xk, short* __restrict__ xv) {
  int z = blockIdx.z;
  const float* A = (z == 0) ? q : (z == 1) ? k : v;
  const short* B = (z == 0) ? wq : (z == 1) ? wk : wv;
  short* C = (z == 0) ? xq : (z == 1) ? xk : xv;
  float scale = (z == 0) ? 0.125f : 1.0f;  // fold 1/sqrt(Dh) into Xq
  gemm_body<true, true>(A, B, C, scale);
}

__global__ __launch_bounds__(256) void final_gemm(
    const short* __restrict__ oa, const short* __restrict__ wo,
    float* __restrict__ out) {
  gemm_body<false, false>(oa, wo, out, 1.0f);
}

// ---------------------------------------------------------------------------
// Causal flash attention. Per block: 64 q rows (4 waves x 16), per (b,h).
// K tile + V^T tile staged in swizzled LDS; online softmax in registers;
// P round-trips through per-wave LDS to reach A-fragment layout.
// ---------------------------------------------------------------------------
__global__ __launch_bounds__(256) void attn_k(
    const short* __restrict__ Xq, const short* __restrict__ Xk,
    const short* __restrict__ Xv, short* __restrict__ Oa) {
  __shared__ __align__(16) short sK[64 * 64];
  __shared__ __align__(16) short sVT[64 * 64];
  __shared__ __align__(16) short sP[4][16 * 64];

  const int tid = threadIdx.x;
  const int lane = tid & 63;
  const int wid = tid >> 6;
  const int l15 = lane & 15, lq = lane >> 4;
  const int qt = blockIdx.x;  // 0..31
  const int bh = blockIdx.y;  // 0..63
  const int b = bh >> 4, h = bh & 15;

  const short* Q = Xq + (size_t)bh * 2048 * 64;
  const short* K = Xk + (size_t)bh * 2048 * 64;
  const short* V = Xv + (size_t)bh * 2048 * 64;

  const int qrow0 = qt * 64 + wid * 16;

  // Q fragments held in registers for the whole block (Xq is pre-scaled)
  short8 qf[2];
#pragma unroll
  for (int ks = 0; ks < 2; ++ks)
    qf[ks] = *(const short8*)(Q + (size_t)(qrow0 + l15) * 64 + ks * 32 + lq * 8);

  float m_run[4], l_run[4];
  f32x4 acc_o[4] = {};
#pragma unroll
  for (int r = 0; r < 4; ++r) { m_run[r] = -1e30f; l_run[r] = 0.f; }

  const int ntiles = qt + 1;
  for (int kt = 0; kt < ntiles; ++kt) {
    const int kv0 = kt * 64;
    // ---- stage K (row-major) and V^T, both XOR-swizzled ----
#pragma unroll
    for (int t = 0; t < 2; ++t) {
      int c = tid + t * 256;
      int row = c >> 3, col = (c & 7) * 8;
      short8 kv = *(const short8*)(K + (size_t)(kv0 + row) * 64 + col);
      int off = (row * 128 + col * 2) ^ ((row & 7) << 4);
      *(short8*)((char*)sK + off) = kv;
      short8 vv = *(const short8*)(V + (size_t)(kv0 + row) * 64 + col);
#pragma unroll
      for (int i = 0; i < 8; ++i) {
        int vr = col + i;  // dh
        int vc = row;      // key
        int voff = (vr * 128 + vc * 2) ^ ((vr & 7) << 4);
        *(short*)((char*)sVT + voff) = vv[i];
      }
    }
    __syncthreads();

    // ---- QK^T: S[16 q][64 key] ----
    f32x4 sc[4] = {};
#pragma unroll
    for (int ks = 0; ks < 2; ++ks) {
      short8 kf[4];
#pragma unroll
      for (int nt = 0; nt < 4; ++nt) {
        int row = nt * 16 + l15;
        int off = (row * 128 + ks * 64 + lq * 16) ^ ((row & 7) << 4);
        kf[nt] = *(const short8*)((const char*)sK + off);
      }
#pragma unroll
      for (int nt = 0; nt < 4; ++nt)
        sc[nt] = __builtin_amdgcn_mfma_f32_16x16x32_bf16(qf[ks], kf[nt], sc[nt], 0, 0, 0);
    }

    // ---- causal mask + online softmax (rows lq*4+r, 16-lane butterflies) ----
    float pv[4][4];  // [r][nt]
    float mx[4], rs[4];
#pragma unroll
    for (int r = 0; r < 4; ++r) {
      int qg = qrow0 + lq * 4 + r;
      float m = -1e30f;
#pragma unroll
      for (int nt = 0; nt < 4; ++nt) {
        int key = kv0 + nt * 16 + l15;
        float s = sc[nt][r];
        if (key > qg) s = -1e30f;
        pv[r][nt] = s;
        m = fmaxf(m, s);
      }
      mx[r] = m;
    }
#pragma unroll
    for (int o = 1; o < 16; o <<= 1)
#pragma unroll
      for (int r = 0; r < 4; ++r) mx[r] = fmaxf(mx[r], __shfl_xor(mx[r], o));

#pragma unroll
    for (int r = 0; r < 4; ++r) {
      float m_new = fmaxf(m_run[r], mx[r]);
      float corr = __expf(m_run[r] - m_new);
      float rsum = 0.f;
#pragma unroll
      for (int nt = 0; nt < 4; ++nt) {
        float p = __expf(pv[r][nt] - m_new);
        pv[r][nt] = p;
        rsum += p;
      }
      rs[r] = rsum;
      m_run[r] = m_new;
      l_run[r] *= corr;
#pragma unroll
      for (int nt = 0; nt < 4; ++nt) acc_o[nt][r] *= corr;
    }
#pragma unroll
    for (int o = 1; o < 16; o <<= 1)
#pragma unroll
      for (int r = 0; r < 4; ++r) rs[r] += __shfl_xor(rs[r], o);
#pragma unroll
    for (int r = 0; r < 4; ++r) l_run[r] += rs[r];

    // ---- P -> per-wave LDS (A-fragment layout), swizzled ----
    short* sPw = sP[wid];
#pragma unroll
    for (int r = 0; r < 4; ++r) {
      int qlocal = lq * 4 + r;
#pragma unroll
      for (int nt = 0; nt < 4; ++nt) {
        int keyl = nt * 16 + l15;
        int off = (qlocal * 128 + keyl * 2) ^ ((qlocal & 7) << 4);
        *(short*)((char*)sPw + off) = f2bf(pv[r][nt]);
      }
    }

    // ---- PV: O[16 q][64 dh] += P @ V ----
#pragma unroll
    for (int ks = 0; ks < 2; ++ks) {
      int prow = l15;
      int poff = (prow * 128 + ks * 64 + lq * 16) ^ ((prow & 7) << 4);
      short8 pf = *(const short8*)((const char*)sPw + poff);
#pragma unroll
      for (int nt = 0; nt < 4; ++nt) {
        int vrow = nt * 16 + l15;
        int voff = (vrow * 128 + ks * 64 + lq * 16) ^ ((vrow & 7) << 4);
        short8 vf = *(const short8*)((const char*)sVT + voff);
        acc_o[nt] = __builtin_amdgcn_mfma_f32_16x16x32_bf16(pf, vf, acc_o[nt], 0, 0, 0);
      }
    }
    __syncthreads();
  }

  // ---- epilogue: O /= l, write bf16 [B,S,D] ----
#pragma unroll
  for (int nt = 0; nt < 4; ++nt) {
#pragma unroll
    for (int r = 0; r < 4; ++r) {
      int srow = qrow0 + lq * 4 + r;
      int dh = nt * 16 + l15;
      float val = acc_o[nt][r] / l_run[r];
      Oa[((size_t)(b * 2048 + srow)) * 1024 + h * 64 + dh] = f2bf(val);
    }
  }
}

// ---------------------------------------------------------------------------
extern "C" void kernel_launch(void* const* d_in, const int* in_sizes, int n_in,
                              void* d_out, int out_size, void* d_ws,
                              size_t ws_size, hipStream_t stream) {
  const float* q = (const float*)d_in[0];
  const float* k = (const float*)d_in[1];
  const float* v = (const float*)d_in[2];
  const float* Wq = (const float*)d_in[3];
  const float* Wk = (const float*)d_in[4];
  const float* Wv = (const float*)d_in[5];
  const float* Wo = (const float*)d_in[6];

  char* ws = (char*)d_ws;
  short* wq_b = (short*)(ws + (0ull << 20));   // 2 MB
  short* wk_b = (short*)(ws + (2ull << 20));
  short* wv_b = (short*)(ws + (4ull << 20));
  short* wo_b = (short*)(ws + (6ull << 20));
  short* xq = (short*)(ws + (8ull << 20));     // 16 MB, [B,H,S,Dh] bf16
  short* xk = (short*)(ws + (24ull << 20));
  short* xv = (short*)(ws + (40ull << 20));
  short* oa = (short*)(ws + (56ull << 20));    // 16 MB, [B,S,D] bf16

  convert_w<<<dim3(1024, 1, 4), 256, 0, stream>>>(Wq, Wk, Wv, Wo, wq_b);
  proj_gemm<<<dim3(8, 64, 3), 256, 0, stream>>>(q, k, v, wq_b, wk_b, wv_b,
                                                xq, xk, xv);
  attn_k<<<dim3(32, 64), 256, 0, stream>>>(xq, xk, xv, oa);
  final_gemm<<<dim3(8, 64), 256, 0, stream>>>(oa, wo_b, (float*)d_out);
}

// Round 2
// 387.431 us; speedup vs baseline: 1.1956x; 1.1956x over previous
//
#include <hip/hip_runtime.h>
#include <hip/hip_bf16.h>

#define DI __device__ __forceinline__

typedef __attribute__((ext_vector_type(8))) short short8;
typedef __attribute__((ext_vector_type(4))) short short4v;
typedef __attribute__((ext_vector_type(4))) float f32x4;

// RNE float -> bf16 (bit trick; inputs are finite)
DI short f2bf(float f) {
  unsigned u = __builtin_bit_cast(unsigned, f);
  unsigned r = u + 0x7fffu + ((u >> 16) & 1u);
  return (short)(r >> 16);
}

// ---------------------------------------------------------------------------
// Weight conversion: 4 x [1024x1024] fp32 -> bf16 (contiguous in ws)
// ---------------------------------------------------------------------------
__global__ __launch_bounds__(256) void convert_w(
    const float* __restrict__ wq, const float* __restrict__ wk,
    const float* __restrict__ wv, const float* __restrict__ wo,
    short* __restrict__ dst) {
  int z = blockIdx.z;
  const float* src = (z == 0) ? wq : (z == 1) ? wk : (z == 2) ? wv : wo;
  short* d = dst + (size_t)z * 1024 * 1024;
  int i = (blockIdx.x * 256 + threadIdx.x) * 4;
  float4 f = *(const float4*)(src + i);
  short4v v;
  v[0] = f2bf(f.x); v[1] = f2bf(f.y); v[2] = f2bf(f.z); v[3] = f2bf(f.w);
  *(short4v*)(d + i) = v;
}

// ---------------------------------------------------------------------------
// GEMM: C[m][n] = sum_k A[m][k] * B[n][k]   (A: [8192][1024], B: [1024][1024])
// 128x128 tile, BK=64, 4 waves x (64x64), mfma 16x16x32 bf16, XOR-swizzled LDS
// ---------------------------------------------------------------------------
template <bool A_FP32, bool OUT_HEAD>
DI void gemm_body(const void* __restrict__ Ap, const short* __restrict__ Bp,
                  void* __restrict__ Cp, float scale) {
  __shared__ __align__(16) short sA[128 * 64];
  __shared__ __align__(16) short sB[128 * 64];

  const int tid = threadIdx.x;
  const int lane = tid & 63;
  const int wid = tid >> 6;
  const int wm = wid >> 1, wn = wid & 1;
  const int bm = blockIdx.y * 128, bn = blockIdx.x * 128;
  const int l15 = lane & 15, lq = lane >> 4;

  f32x4 acc[4][4] = {};

  for (int k0 = 0; k0 < 1024; k0 += 64) {
    if (A_FP32) {
      const float* A = (const float*)Ap;
#pragma unroll
      for (int t = 0; t < 4; ++t) {
        int c = tid + t * 256;
        int row = c >> 3, col = (c & 7) * 8;
        const float* src = A + (size_t)(bm + row) * 1024 + k0 + col;
        float4 f0 = *(const float4*)src;
        float4 f1 = *(const float4*)(src + 4);
        short8 vv;
        vv[0] = f2bf(f0.x); vv[1] = f2bf(f0.y); vv[2] = f2bf(f0.z); vv[3] = f2bf(f0.w);
        vv[4] = f2bf(f1.x); vv[5] = f2bf(f1.y); vv[6] = f2bf(f1.z); vv[7] = f2bf(f1.w);
        int off = (row * 128 + col * 2) ^ ((row & 7) << 4);
        *(short8*)((char*)sA + off) = vv;
      }
    } else {
      const short* A = (const short*)Ap;
#pragma unroll
      for (int t = 0; t < 4; ++t) {
        int c = tid + t * 256;
        int row = c >> 3, col = (c & 7) * 8;
        short8 vv = *(const short8*)(A + (size_t)(bm + row) * 1024 + k0 + col);
        int off = (row * 128 + col * 2) ^ ((row & 7) << 4);
        *(short8*)((char*)sA + off) = vv;
      }
    }
#pragma unroll
    for (int t = 0; t < 4; ++t) {
      int c = tid + t * 256;
      int row = c >> 3, col = (c & 7) * 8;
      short8 vv = *(const short8*)(Bp + (size_t)(bn + row) * 1024 + k0 + col);
      int off = (row * 128 + col * 2) ^ ((row & 7) << 4);
      *(short8*)((char*)sB + off) = vv;
    }
    __syncthreads();

#pragma unroll
    for (int ks = 0; ks < 2; ++ks) {
      short8 a[4], b[4];
#pragma unroll
      for (int mt = 0; mt < 4; ++mt) {
        int row = wm * 64 + mt * 16 + l15;
        int off = (row * 128 + ks * 64 + lq * 16) ^ ((row & 7) << 4);
        a[mt] = *(const short8*)((const char*)sA + off);
      }
#pragma unroll
      for (int nt = 0; nt < 4; ++nt) {
        int row = wn * 64 + nt * 16 + l15;
        int off = (row * 128 + ks * 64 + lq * 16) ^ ((row & 7) << 4);
        b[nt] = *(const short8*)((const char*)sB + off);
      }
#pragma unroll
      for (int mt = 0; mt < 4; ++mt)
#pragma unroll
        for (int nt = 0; nt < 4; ++nt)
          acc[mt][nt] = __builtin_amdgcn_mfma_f32_16x16x32_bf16(
              a[mt], b[nt], acc[mt][nt], 0, 0, 0);
    }
    __syncthreads();
  }

#pragma unroll
  for (int mt = 0; mt < 4; ++mt) {
#pragma unroll
    for (int nt = 0; nt < 4; ++nt) {
#pragma unroll
      for (int r = 0; r < 4; ++r) {
        int rowg = bm + wm * 64 + mt * 16 + lq * 4 + r;
        int colg = bn + wn * 64 + nt * 16 + l15;
        float val = acc[mt][nt][r] * scale;
        if (OUT_HEAD) {
          int b = rowg >> 11, s = rowg & 2047;
          int h = colg >> 6, dh = colg & 63;
          ((short*)Cp)[((size_t)(b * 16 + h) * 2048 + s) * 64 + dh] = f2bf(val);
        } else {
          ((float*)Cp)[(size_t)rowg * 1024 + colg] = val;
        }
      }
    }
  }
}

__global__ __launch_bounds__(256) void proj_gemm(
    const float* __restrict__ q, const float* __restrict__ k,
    const float* __restrict__ v, const short* __restrict__ wq,
    const short* __restrict__ wk, const short* __restrict__ wv,
    short* __restrict__ xq, short* __restrict__ xk, short* __restrict__ xv) {
  int z = blockIdx.z;
  const float* A = (z == 0) ? q : (z == 1) ? k : v;
  const short* B = (z == 0) ? wq : (z == 1) ? wk : wv;
  short* C = (z == 0) ? xq : (z == 1) ? xk : xv;
  float scale = (z == 0) ? 0.125f : 1.0f;  // fold 1/sqrt(Dh) into Xq
  gemm_body<true, true>(A, B, C, scale);
}

__global__ __launch_bounds__(256) void final_gemm(
    const short* __restrict__ oa, const short* __restrict__ wo,
    float* __restrict__ out) {
  gemm_body<false, false>(oa, wo, out, 1.0f);
}

// ---------------------------------------------------------------------------
// V transpose: Xv [B,H,S,64] -> XvT [B,H,64,S]. 64x64 tiles through LDS.
// Swizzle keyed on (r ^ (r>>3)) so column reads (row-stride 8) are
// conflict-free as well as the row writes.
// ---------------------------------------------------------------------------
__global__ __launch_bounds__(256) void transpose_v(
    const short* __restrict__ Xv, short* __restrict__ XvT) {
  __shared__ __align__(16) short sT[64 * 64];
  const int tid = threadIdx.x;
  const int bh = blockIdx.y;
  const int s0 = blockIdx.x * 64;
  const short* src = Xv + ((size_t)bh * 2048 + s0) * 64;
  short* dst = XvT + (size_t)bh * 64 * 2048 + s0;
#pragma unroll
  for (int t = 0; t < 2; ++t) {
    int c = tid + t * 256;
    int r = c >> 3, c8 = (c & 7) * 8;
    short8 v = *(const short8*)(src + (size_t)r * 64 + c8);
    int off = (r * 128 + c8 * 2) ^ (((r ^ (r >> 3)) & 7) << 4);
    *(short8*)((char*)sT + off) = v;
  }
  __syncthreads();
#pragma unroll
  for (int u = 0; u < 2; ++u) {
    int c = tid + u * 256;
    int dh = c >> 3;
    int sl = (c & 7) * 8;
    short8 o;
#pragma unroll
    for (int i = 0; i < 8; ++i) {
      int r = sl + i;
      int off = (r * 128 + dh * 2) ^ (((r ^ (r >> 3)) & 7) << 4);
      o[i] = *(const short*)((const char*)sT + off);
    }
    *(short8*)(dst + (size_t)dh * 2048 + sl) = o;
  }
}

// ---------------------------------------------------------------------------
// Causal flash attention. Per block: 64 q rows (4 waves x 16), per (b,h).
// K tile [key][d] and VT tile [dh][key] staged vectorized + XOR-swizzled.
// T14: next tile's global loads prefetched into regs during compute.
// ---------------------------------------------------------------------------
__global__ __launch_bounds__(256) void attn_k(
    const short* __restrict__ Xq, const short* __restrict__ Xk,
    const short* __restrict__ XvT, short* __restrict__ Oa) {
  __shared__ __align__(16) short sK[64 * 64];
  __shared__ __align__(16) short sVT[64 * 64];
  __shared__ __align__(16) short sP[4][16 * 64];

  const int tid = threadIdx.x;
  const int lane = tid & 63;
  const int wid = tid >> 6;
  const int l15 = lane & 15, lq = lane >> 4;
  const int qt = blockIdx.x;  // 0..31
  const int bh = blockIdx.y;  // 0..63
  const int b = bh >> 4, h = bh & 15;

  const short* Q = Xq + (size_t)bh * 2048 * 64;
  const short* K = Xk + (size_t)bh * 2048 * 64;
  const short* VT = XvT + (size_t)bh * 64 * 2048;

  const int qrow0 = qt * 64 + wid * 16;

  // Q fragments in registers for the whole block (Xq pre-scaled by 1/8)
  short8 qf[2];
#pragma unroll
  for (int ks = 0; ks < 2; ++ks)
    qf[ks] = *(const short8*)(Q + (size_t)(qrow0 + l15) * 64 + ks * 32 + lq * 8);

  // per-thread staging coordinates
  const int srow = tid >> 3;        // 0..31 (t adds 32)
  const int scol = (tid & 7) * 8;   // 0..56
  const int soff0 = (srow * 128 + scol * 2) ^ ((srow & 7) << 4);
  const int soff1 = ((srow + 32) * 128 + scol * 2) ^ ((srow & 7) << 4);

  short8 kreg[2], vreg[2];
  // prefetch tile 0
  kreg[0] = *(const short8*)(K + (size_t)srow * 64 + scol);
  kreg[1] = *(const short8*)(K + (size_t)(srow + 32) * 64 + scol);
  vreg[0] = *(const short8*)(VT + (size_t)srow * 2048 + scol);
  vreg[1] = *(const short8*)(VT + (size_t)(srow + 32) * 2048 + scol);

  float m_run[4], l_run[4];
  f32x4 acc_o[4] = {};
#pragma unroll
  for (int r = 0; r < 4; ++r) { m_run[r] = -1e30f; l_run[r] = 0.f; }

  const int ntiles = qt + 1;
  for (int kt = 0; kt < ntiles; ++kt) {
    const int kv0 = kt * 64;
    // ---- write staged regs -> LDS (swizzled, vectorized) ----
    *(short8*)((char*)sK + soff0) = kreg[0];
    *(short8*)((char*)sK + soff1) = kreg[1];
    *(short8*)((char*)sVT + soff0) = vreg[0];
    *(short8*)((char*)sVT + soff1) = vreg[1];
    __syncthreads();

    // ---- T14 prefetch: issue next tile's global loads now ----
    if (kt + 1 < ntiles) {
      const int kn = kv0 + 64;
      kreg[0] = *(const short8*)(K + (size_t)(kn + srow) * 64 + scol);
      kreg[1] = *(const short8*)(K + (size_t)(kn + srow + 32) * 64 + scol);
      vreg[0] = *(const short8*)(VT + (size_t)srow * 2048 + kn + scol);
      vreg[1] = *(const short8*)(VT + (size_t)(srow + 32) * 2048 + kn + scol);
    }

    // ---- QK^T: S[16 q][64 key] ----
    f32x4 sc[4] = {};
#pragma unroll
    for (int ks = 0; ks < 2; ++ks) {
      short8 kf[4];
#pragma unroll
      for (int nt = 0; nt < 4; ++nt) {
        int row = nt * 16 + l15;
        int off = (row * 128 + ks * 64 + lq * 16) ^ ((row & 7) << 4);
        kf[nt] = *(const short8*)((const char*)sK + off);
      }
#pragma unroll
      for (int nt = 0; nt < 4; ++nt)
        sc[nt] = __builtin_amdgcn_mfma_f32_16x16x32_bf16(qf[ks], kf[nt], sc[nt], 0, 0, 0);
    }

    // ---- causal mask (diag tile only) + online softmax ----
    float pv[4][4];
    float mx[4], rs[4];
    const bool diag = (kt == qt);
#pragma unroll
    for (int r = 0; r < 4; ++r) {
      float m = -1e30f;
#pragma unroll
      for (int nt = 0; nt < 4; ++nt) {
        float s = sc[nt][r];
        if (diag) {
          int qg = qrow0 + lq * 4 + r;
          int key = kv0 + nt * 16 + l15;
          if (key > qg) s = -1e30f;
        }
        pv[r][nt] = s;
        m = fmaxf(m, s);
      }
      mx[r] = m;
    }
#pragma unroll
    for (int o = 1; o < 16; o <<= 1)
#pragma unroll
      for (int r = 0; r < 4; ++r) mx[r] = fmaxf(mx[r], __shfl_xor(mx[r], o));

#pragma unroll
    for (int r = 0; r < 4; ++r) {
      float m_new = fmaxf(m_run[r], mx[r]);
      float corr = __expf(m_run[r] - m_new);
      float rsum = 0.f;
#pragma unroll
      for (int nt = 0; nt < 4; ++nt) {
        float p = __expf(pv[r][nt] - m_new);
        pv[r][nt] = p;
        rsum += p;
      }
      rs[r] = rsum;
      m_run[r] = m_new;
      l_run[r] *= corr;
#pragma unroll
      for (int nt = 0; nt < 4; ++nt) acc_o[nt][r] *= corr;
    }
#pragma unroll
    for (int o = 1; o < 16; o <<= 1)
#pragma unroll
      for (int r = 0; r < 4; ++r) rs[r] += __shfl_xor(rs[r], o);
#pragma unroll
    for (int r = 0; r < 4; ++r) l_run[r] += rs[r];

    // ---- P -> per-wave LDS (A-fragment layout), swizzled ----
    short* sPw = sP[wid];
#pragma unroll
    for (int r = 0; r < 4; ++r) {
      int qlocal = lq * 4 + r;
#pragma unroll
      for (int nt = 0; nt < 4; ++nt) {
        int keyl = nt * 16 + l15;
        int off = (qlocal * 128 + keyl * 2) ^ ((qlocal & 7) << 4);
        *(short*)((char*)sPw + off) = f2bf(pv[r][nt]);
      }
    }

    // ---- PV: O[16 q][64 dh] += P @ V ----
#pragma unroll
    for (int ks = 0; ks < 2; ++ks) {
      int poff = (l15 * 128 + ks * 64 + lq * 16) ^ ((l15 & 7) << 4);
      short8 pf = *(const short8*)((const char*)sPw + poff);
#pragma unroll
      for (int nt = 0; nt < 4; ++nt) {
        int vrow = nt * 16 + l15;
        int voff = (vrow * 128 + ks * 64 + lq * 16) ^ ((vrow & 7) << 4);
        short8 vf = *(const short8*)((const char*)sVT + voff);
        acc_o[nt] = __builtin_amdgcn_mfma_f32_16x16x32_bf16(pf, vf, acc_o[nt], 0, 0, 0);
      }
    }
    __syncthreads();
  }

  // ---- epilogue: O /= l, write bf16 [B,S,D] ----
#pragma unroll
  for (int nt = 0; nt < 4; ++nt) {
#pragma unroll
    for (int r = 0; r < 4; ++r) {
      int srowg = qrow0 + lq * 4 + r;
      int dh = nt * 16 + l15;
      float val = acc_o[nt][r] / l_run[r];
      Oa[((size_t)(b * 2048 + srowg)) * 1024 + h * 64 + dh] = f2bf(val);
    }
  }
}

// ---------------------------------------------------------------------------
extern "C" void kernel_launch(void* const* d_in, const int* in_sizes, int n_in,
                              void* d_out, int out_size, void* d_ws,
                              size_t ws_size, hipStream_t stream) {
  const float* q = (const float*)d_in[0];
  const float* k = (const float*)d_in[1];
  const float* v = (const float*)d_in[2];
  const float* Wq = (const float*)d_in[3];
  const float* Wk = (const float*)d_in[4];
  const float* Wv = (const float*)d_in[5];
  const float* Wo = (const float*)d_in[6];

  char* ws = (char*)d_ws;
  short* wq_b = (short*)(ws + (0ull << 20));   // 2 MB
  short* wk_b = (short*)(ws + (2ull << 20));
  short* wv_b = (short*)(ws + (4ull << 20));
  short* wo_b = (short*)(ws + (6ull << 20));
  short* xq  = (short*)(ws + (8ull << 20));    // 16 MB, [B,H,S,Dh] bf16
  short* xk  = (short*)(ws + (24ull << 20));
  short* xv  = (short*)(ws + (40ull << 20));   // dead after transpose_v
  short* xvT = (short*)(ws + (56ull << 20));   // 16 MB, [B,H,Dh,S] bf16
  short* oa  = xv;                             // reuse dead region

  convert_w<<<dim3(1024, 1, 4), 256, 0, stream>>>(Wq, Wk, Wv, Wo, wq_b);
  proj_gemm<<<dim3(8, 64, 3), 256, 0, stream>>>(q, k, v, wq_b, wk_b, wv_b,
                                                xq, xk, xv);
  transpose_v<<<dim3(32, 64), 256, 0, stream>>>(xv, xvT);
  attn_k<<<dim3(32, 64), 256, 0, stream>>>(xq, xk, xvT, oa);
  final_gemm<<<dim3(8, 64), 256, 0, stream>>>(oa, wo_b, (float*)d_out);
}

// Round 3
// 236.976 us; speedup vs baseline: 1.9548x; 1.6349x over previous
//
#include <hip/hip_runtime.h>
#include <hip/hip_bf16.h>

#define DI __device__ __forceinline__

typedef __attribute__((ext_vector_type(8))) short short8;
typedef __attribute__((ext_vector_type(4))) short short4v;
typedef __attribute__((ext_vector_type(4))) float f32x4;

// RNE float -> bf16 (bit trick; inputs are finite)
DI short f2bf(float f) {
  unsigned u = __builtin_bit_cast(unsigned, f);
  unsigned r = u + 0x7fffu + ((u >> 16) & 1u);
  return (short)(r >> 16);
}

// ---------------------------------------------------------------------------
// Weight conversion: 4 x [1024x1024] fp32 -> bf16 (contiguous in ws)
// ---------------------------------------------------------------------------
__global__ __launch_bounds__(256) void convert_w(
    const float* __restrict__ wq, const float* __restrict__ wk,
    const float* __restrict__ wv, const float* __restrict__ wo,
    short* __restrict__ dst) {
  int z = blockIdx.z;
  const float* src = (z == 0) ? wq : (z == 1) ? wk : (z == 2) ? wv : wo;
  short* d = dst + (size_t)z * 1024 * 1024;
  int i = (blockIdx.x * 256 + threadIdx.x) * 4;
  float4 f = *(const float4*)(src + i);
  short4v v;
  v[0] = f2bf(f.x); v[1] = f2bf(f.y); v[2] = f2bf(f.z); v[3] = f2bf(f.w);
  *(short4v*)(d + i) = v;
}

// ---------------------------------------------------------------------------
// GEMM: C[m][n] = sum_k A[m][k] * B[n][k]   (A: [8192][1024], B: [1024][1024])
// 128x128 tile, BK=64, 4 waves x (64x64), mfma 16x16x32 bf16, XOR-swizzled LDS
// ---------------------------------------------------------------------------
template <bool A_FP32, bool OUT_HEAD>
DI void gemm_body(const void* __restrict__ Ap, const short* __restrict__ Bp,
                  void* __restrict__ Cp, float scale) {
  __shared__ __align__(16) short sA[128 * 64];
  __shared__ __align__(16) short sB[128 * 64];

  const int tid = threadIdx.x;
  const int lane = tid & 63;
  const int wid = tid >> 6;
  const int wm = wid >> 1, wn = wid & 1;
  const int bm = blockIdx.y * 128, bn = blockIdx.x * 128;
  const int l15 = lane & 15, lq = lane >> 4;

  f32x4 acc[4][4] = {};

  for (int k0 = 0; k0 < 1024; k0 += 64) {
    if (A_FP32) {
      const float* A = (const float*)Ap;
#pragma unroll
      for (int t = 0; t < 4; ++t) {
        int c = tid + t * 256;
        int row = c >> 3, col = (c & 7) * 8;
        const float* src = A + (size_t)(bm + row) * 1024 + k0 + col;
        float4 f0 = *(const float4*)src;
        float4 f1 = *(const float4*)(src + 4);
        short8 vv;
        vv[0] = f2bf(f0.x); vv[1] = f2bf(f0.y); vv[2] = f2bf(f0.z); vv[3] = f2bf(f0.w);
        vv[4] = f2bf(f1.x); vv[5] = f2bf(f1.y); vv[6] = f2bf(f1.z); vv[7] = f2bf(f1.w);
        int off = (row * 128 + col * 2) ^ ((row & 7) << 4);
        *(short8*)((char*)sA + off) = vv;
      }
    } else {
      const short* A = (const short*)Ap;
#pragma unroll
      for (int t = 0; t < 4; ++t) {
        int c = tid + t * 256;
        int row = c >> 3, col = (c & 7) * 8;
        short8 vv = *(const short8*)(A + (size_t)(bm + row) * 1024 + k0 + col);
        int off = (row * 128 + col * 2) ^ ((row & 7) << 4);
        *(short8*)((char*)sA + off) = vv;
      }
    }
#pragma unroll
    for (int t = 0; t < 4; ++t) {
      int c = tid + t * 256;
      int row = c >> 3, col = (c & 7) * 8;
      short8 vv = *(const short8*)(Bp + (size_t)(bn + row) * 1024 + k0 + col);
      int off = (row * 128 + col * 2) ^ ((row & 7) << 4);
      *(short8*)((char*)sB + off) = vv;
    }
    __syncthreads();

#pragma unroll
    for (int ks = 0; ks < 2; ++ks) {
      short8 a[4], b[4];
#pragma unroll
      for (int mt = 0; mt < 4; ++mt) {
        int row = wm * 64 + mt * 16 + l15;
        int off = (row * 128 + ks * 64 + lq * 16) ^ ((row & 7) << 4);
        a[mt] = *(const short8*)((const char*)sA + off);
      }
#pragma unroll
      for (int nt = 0; nt < 4; ++nt) {
        int row = wn * 64 + nt * 16 + l15;
        int off = (row * 128 + ks * 64 + lq * 16) ^ ((row & 7) << 4);
        b[nt] = *(const short8*)((const char*)sB + off);
      }
#pragma unroll
      for (int mt = 0; mt < 4; ++mt)
#pragma unroll
        for (int nt = 0; nt < 4; ++nt)
          acc[mt][nt] = __builtin_amdgcn_mfma_f32_16x16x32_bf16(
              a[mt], b[nt], acc[mt][nt], 0, 0, 0);
    }
    __syncthreads();
  }

#pragma unroll
  for (int mt = 0; mt < 4; ++mt) {
#pragma unroll
    for (int nt = 0; nt < 4; ++nt) {
#pragma unroll
      for (int r = 0; r < 4; ++r) {
        int rowg = bm + wm * 64 + mt * 16 + lq * 4 + r;
        int colg = bn + wn * 64 + nt * 16 + l15;
        float val = acc[mt][nt][r] * scale;
        if (OUT_HEAD) {
          int b = rowg >> 11, s = rowg & 2047;
          int h = colg >> 6, dh = colg & 63;
          ((short*)Cp)[((size_t)(b * 16 + h) * 2048 + s) * 64 + dh] = f2bf(val);
        } else {
          ((float*)Cp)[(size_t)rowg * 1024 + colg] = val;
        }
      }
    }
  }
}

__global__ __launch_bounds__(256) void proj_gemm(
    const float* __restrict__ q, const float* __restrict__ k,
    const float* __restrict__ v, const short* __restrict__ wq,
    const short* __restrict__ wk, const short* __restrict__ wv,
    short* __restrict__ xq, short* __restrict__ xk, short* __restrict__ xv) {
  int z = blockIdx.z;
  const float* A = (z == 0) ? q : (z == 1) ? k : v;
  const short* B = (z == 0) ? wq : (z == 1) ? wk : wv;
  short* C = (z == 0) ? xq : (z == 1) ? xk : xv;
  float scale = (z == 0) ? 0.125f : 1.0f;  // fold 1/sqrt(Dh) into Xq
  gemm_body<true, true>(A, B, C, scale);
}

__global__ __launch_bounds__(256) void final_gemm(
    const short* __restrict__ oa, const short* __restrict__ wo,
    float* __restrict__ out) {
  gemm_body<false, false>(oa, wo, out, 1.0f);
}

// ---------------------------------------------------------------------------
// V transpose: Xv [B,H,S,64] -> XvT [B,H,64,S]. 64x64 tiles through LDS.
// ---------------------------------------------------------------------------
__global__ __launch_bounds__(256) void transpose_v(
    const short* __restrict__ Xv, short* __restrict__ XvT) {
  __shared__ __align__(16) short sT[64 * 64];
  const int tid = threadIdx.x;
  const int bh = blockIdx.y;
  const int s0 = blockIdx.x * 64;
  const short* src = Xv + ((size_t)bh * 2048 + s0) * 64;
  short* dst = XvT + (size_t)bh * 64 * 2048 + s0;
#pragma unroll
  for (int t = 0; t < 2; ++t) {
    int c = tid + t * 256;
    int r = c >> 3, c8 = (c & 7) * 8;
    short8 v = *(const short8*)(src + (size_t)r * 64 + c8);
    int off = (r * 128 + c8 * 2) ^ (((r ^ (r >> 3)) & 7) << 4);
    *(short8*)((char*)sT + off) = v;
  }
  __syncthreads();
#pragma unroll
  for (int u = 0; u < 2; ++u) {
    int c = tid + u * 256;
    int dh = c >> 3;
    int sl = (c & 7) * 8;
    short8 o;
#pragma unroll
    for (int i = 0; i < 8; ++i) {
      int r = sl + i;
      int off = (r * 128 + dh * 2) ^ (((r ^ (r >> 3)) & 7) << 4);
      o[i] = *(const short*)((const char*)sT + off);
    }
    *(short8*)(dst + (size_t)dh * 2048 + sl) = o;
  }
}

// ---------------------------------------------------------------------------
// Causal flash attention, swapped-QK^T form.
// Block: 256 thr = 4 waves x 16 q-rows; TWO q-tiles (i, 31-i) sequentially
// (perfect load balance: 33 KV tiles per block). Grid 1024 flat: id&63 = bh
// so all blocks of one (b,h) share an XCD (K/V L2 reuse).
// QK^T computed as mfma(K,Q) -> lane owns ONE q-row (q = lane&15): scalar
// online-softmax state, 4 shuffles/tile, vectorized P->LDS (4x ds_write_b64).
// PV computes O^T = mfma(V^T, P). T14 reg prefetch of next K/V tile.
// ---------------------------------------------------------------------------
__global__ __launch_bounds__(256) void attn_k(
    const short* __restrict__ Xq, const short* __restrict__ Xk,
    const short* __restrict__ XvT, short* __restrict__ Oa) {
  __shared__ __align__(16) short sK[64 * 64];
  __shared__ __align__(16) short sVT[64 * 64];
  __shared__ __align__(16) short sP[4][16 * 64];

  const int tid = threadIdx.x;
  const int lane = tid & 63;
  const int wid = tid >> 6;
  const int l15 = lane & 15, lq = lane >> 4;
  const int bid = blockIdx.x;
  const int ipair = bid >> 6;  // 0..15
  const int bh = bid & 63;     // same-bh blocks land on same XCD
  const int b = bh >> 4, h = bh & 15;

  const short* Q = Xq + (size_t)bh * 2048 * 64;
  const short* K = Xk + (size_t)bh * 2048 * 64;
  const short* VT = XvT + (size_t)bh * 64 * 2048;

  // per-thread staging coordinates
  const int srow = tid >> 3;       // 0..31 (second half adds 32)
  const int scol = (tid & 7) * 8;  // 0..56
  const int soff0 = (srow * 128 + scol * 2) ^ ((srow & 7) << 4);
  const int soff1 = ((srow + 32) * 128 + scol * 2) ^ ((srow & 7) << 4);

  short8 kreg[2], vreg[2];
  // prefetch tile 0 (kv0 = 0)
  kreg[0] = *(const short8*)(K + (size_t)srow * 64 + scol);
  kreg[1] = *(const short8*)(K + (size_t)(srow + 32) * 64 + scol);
  vreg[0] = *(const short8*)(VT + (size_t)srow * 2048 + scol);
  vreg[1] = *(const short8*)(VT + (size_t)(srow + 32) * 2048 + scol);

  short* sPw = sP[wid];

  for (int seg = 0; seg < 2; ++seg) {
    const int qt = seg ? ipair : (31 - ipair);  // long segment first
    const int qrow0 = qt * 64 + wid * 16;
    const int qg = qrow0 + l15;  // this lane's q row

    short8 qf[2];
#pragma unroll
    for (int ks = 0; ks < 2; ++ks)
      qf[ks] = *(const short8*)(Q + (size_t)qg * 64 + ks * 32 + lq * 8);

    float m_run = -1e30f, l_run = 0.f;
    f32x4 acc[4] = {};  // O^T[dh = mt*16+lq*4+r][q = l15]

    for (int kt = 0; kt <= qt; ++kt) {
      const int kv0 = kt * 64;
      // ---- staged regs -> LDS ----
      *(short8*)((char*)sK + soff0) = kreg[0];
      *(short8*)((char*)sK + soff1) = kreg[1];
      *(short8*)((char*)sVT + soff0) = vreg[0];
      *(short8*)((char*)sVT + soff1) = vreg[1];
      __syncthreads();

      // ---- T14 prefetch next tile (possibly next segment's tile 0) ----
      {
        int nkt = kt + 1, nseg = seg;
        if (nkt > qt) { nseg = seg + 1; nkt = 0; }
        if (nseg < 2) {
          const int kn = nkt * 64;
          kreg[0] = *(const short8*)(K + (size_t)(kn + srow) * 64 + scol);
          kreg[1] = *(const short8*)(K + (size_t)(kn + srow + 32) * 64 + scol);
          vreg[0] = *(const short8*)(VT + (size_t)srow * 2048 + kn + scol);
          vreg[1] = *(const short8*)(VT + (size_t)(srow + 32) * 2048 + kn + scol);
        }
      }

      // ---- QK^T swapped: sc[nt][r] = S[key=kv0+nt*16+lq*4+r][q=l15] ----
      f32x4 sc[4] = {};
      __builtin_amdgcn_s_setprio(1);
#pragma unroll
      for (int ks = 0; ks < 2; ++ks) {
        short8 kf[4];
#pragma unroll
        for (int nt = 0; nt < 4; ++nt) {
          int row = nt * 16 + l15;
          int off = (row * 128 + ks * 64 + lq * 16) ^ ((row & 7) << 4);
          kf[nt] = *(const short8*)((const char*)sK + off);
        }
#pragma unroll
        for (int nt = 0; nt < 4; ++nt)
          sc[nt] = __builtin_amdgcn_mfma_f32_16x16x32_bf16(kf[nt], qf[ks], sc[nt], 0, 0, 0);
      }
      __builtin_amdgcn_s_setprio(0);

      // ---- mask + online softmax (scalar state per lane) ----
      float p[4][4];
      float m = -1e30f;
      const bool diag = (kt == qt);
#pragma unroll
      for (int nt = 0; nt < 4; ++nt) {
#pragma unroll
        for (int r = 0; r < 4; ++r) {
          float s = sc[nt][r];
          if (diag && (kv0 + nt * 16 + lq * 4 + r > qg)) s = -1e30f;
          p[nt][r] = s;
          m = fmaxf(m, s);
        }
      }
      m = fmaxf(m, __shfl_xor(m, 16));
      m = fmaxf(m, __shfl_xor(m, 32));

      const float m_new = fmaxf(m_run, m);
      const float corr = __expf(m_run - m_new);
      float rsum = 0.f;
#pragma unroll
      for (int nt = 0; nt < 4; ++nt)
#pragma unroll
        for (int r = 0; r < 4; ++r) {
          float e = __expf(p[nt][r] - m_new);
          p[nt][r] = e;
          rsum += e;
        }
      rsum += __shfl_xor(rsum, 16);
      rsum += __shfl_xor(rsum, 32);
      l_run = l_run * corr + rsum;
      m_run = m_new;
#pragma unroll
      for (int mt = 0; mt < 4; ++mt)
#pragma unroll
        for (int r = 0; r < 4; ++r) acc[mt][r] *= corr;

      // ---- P -> per-wave LDS [q][key], vectorized ds_write_b64 ----
#pragma unroll
      for (int nt = 0; nt < 4; ++nt) {
        short4v pw;
#pragma unroll
        for (int r = 0; r < 4; ++r) pw[r] = f2bf(p[nt][r]);
        int off = (l15 * 128 + nt * 32 + lq * 8) ^ ((l15 & 7) << 4);
        *(short4v*)((char*)sPw + off) = pw;
      }

      // ---- PV: O^T[dh][q] += V^T[dh][key] * P^T[key][q] ----
      __builtin_amdgcn_s_setprio(1);
#pragma unroll
      for (int ks = 0; ks < 2; ++ks) {
        int poff = (l15 * 128 + ks * 64 + lq * 16) ^ ((l15 & 7) << 4);
        short8 pf = *(const short8*)((const char*)sPw + poff);
#pragma unroll
        for (int mt = 0; mt < 4; ++mt) {
          int row = mt * 16 + l15;
          int voff = (row * 128 + ks * 64 + lq * 16) ^ ((row & 7) << 4);
          short8 vf = *(const short8*)((const char*)sVT + voff);
          acc[mt] = __builtin_amdgcn_mfma_f32_16x16x32_bf16(vf, pf, acc[mt], 0, 0, 0);
        }
      }
      __builtin_amdgcn_s_setprio(0);
      __syncthreads();
    }

    // ---- epilogue: O[q][dh] = acc^T / l, packed 8B stores ----
    const float rl = 1.0f / l_run;
    short* orow = Oa + ((size_t)(b * 2048 + qg)) * 1024 + h * 64;
#pragma unroll
    for (int mt = 0; mt < 4; ++mt) {
      short4v o;
#pragma unroll
      for (int r = 0; r < 4; ++r) o[r] = f2bf(acc[mt][r] * rl);
      *(short4v*)(orow + mt * 16 + lq * 4) = o;
    }
  }
}

// ---------------------------------------------------------------------------
extern "C" void kernel_launch(void* const* d_in, const int* in_sizes, int n_in,
                              void* d_out, int out_size, void* d_ws,
                              size_t ws_size, hipStream_t stream) {
  const float* q = (const float*)d_in[0];
  const float* k = (const float*)d_in[1];
  const float* v = (const float*)d_in[2];
  const float* Wq = (const float*)d_in[3];
  const float* Wk = (const float*)d_in[4];
  const float* Wv = (const float*)d_in[5];
  const float* Wo = (const float*)d_in[6];

  char* ws = (char*)d_ws;
  short* wq_b = (short*)(ws + (0ull << 20));   // 2 MB
  short* wk_b = (short*)(ws + (2ull << 20));
  short* wv_b = (short*)(ws + (4ull << 20));
  short* wo_b = (short*)(ws + (6ull << 20));
  short* xq  = (short*)(ws + (8ull << 20));    // 16 MB, [B,H,S,Dh] bf16
  short* xk  = (short*)(ws + (24ull << 20));
  short* xv  = (short*)(ws + (40ull << 20));   // dead after transpose_v
  short* xvT = (short*)(ws + (56ull << 20));   // 16 MB, [B,H,Dh,S] bf16
  short* oa  = xv;                             // reuse dead region

  convert_w<<<dim3(1024, 1, 4), 256, 0, stream>>>(Wq, Wk, Wv, Wo, wq_b);
  proj_gemm<<<dim3(8, 64, 3), 256, 0, stream>>>(q, k, v, wq_b, wk_b, wv_b,
                                                xq, xk, xv);
  transpose_v<<<dim3(32, 64), 256, 0, stream>>>(xv, xvT);
  attn_k<<<dim3(1024), 256, 0, stream>>>(xq, xk, xvT, oa);
  final_gemm<<<dim3(8, 64), 256, 0, stream>>>(oa, wo_b, (float*)d_out);
}

// Round 4
// 200.448 us; speedup vs baseline: 2.3110x; 1.1822x over previous
//
#include <hip/hip_runtime.h>
#include <hip/hip_bf16.h>

#define DI __device__ __forceinline__

typedef __attribute__((ext_vector_type(8))) short short8;
typedef __attribute__((ext_vector_type(4))) short short4v;
typedef __attribute__((ext_vector_type(4))) float f32x4;

// RNE float -> bf16 (bit trick; inputs are finite)
DI short f2bf(float f) {
  unsigned u = __builtin_bit_cast(unsigned, f);
  unsigned r = u + 0x7fffu + ((u >> 16) & 1u);
  return (short)(r >> 16);
}

// async global->LDS, 16B per lane. LDS dest = wave-uniform base + lane*16.
DI void gl16(const short* g, short* l) {
  __builtin_amdgcn_global_load_lds(
      (const __attribute__((address_space(1))) void*)g,
      (__attribute__((address_space(3))) void*)l, 16, 0, 0);
}

// ---------------------------------------------------------------------------
// Weight conversion: 4 x [1024x1024] fp32 -> bf16 (contiguous in ws)
// ---------------------------------------------------------------------------
__global__ __launch_bounds__(256) void convert_w(
    const float* __restrict__ wq, const float* __restrict__ wk,
    const float* __restrict__ wv, const float* __restrict__ wo,
    short* __restrict__ dst) {
  int z = blockIdx.z;
  const float* src = (z == 0) ? wq : (z == 1) ? wk : (z == 2) ? wv : wo;
  short* d = dst + (size_t)z * 1024 * 1024;
  int i = (blockIdx.x * 256 + threadIdx.x) * 4;
  float4 f = *(const float4*)(src + i);
  short4v v;
  v[0] = f2bf(f.x); v[1] = f2bf(f.y); v[2] = f2bf(f.z); v[3] = f2bf(f.w);
  *(short4v*)(d + i) = v;
}

// q/k/v fp32 -> bf16, all three in one launch (grid.z selects)
__global__ __launch_bounds__(256) void convert_x(
    const float* __restrict__ q, const float* __restrict__ k,
    const float* __restrict__ v, short* __restrict__ qb,
    short* __restrict__ kb, short* __restrict__ vb) {
  int z = blockIdx.z;
  const float* src = (z == 0) ? q : (z == 1) ? k : v;
  short* dst = (z == 0) ? qb : (z == 1) ? kb : vb;
  size_t i = ((size_t)blockIdx.x * 256 + threadIdx.x) * 8;
  float4 f0 = *(const float4*)(src + i);
  float4 f1 = *(const float4*)(src + i + 4);
  short8 o;
  o[0] = f2bf(f0.x); o[1] = f2bf(f0.y); o[2] = f2bf(f0.z); o[3] = f2bf(f0.w);
  o[4] = f2bf(f1.x); o[5] = f2bf(f1.y); o[6] = f2bf(f1.z); o[7] = f2bf(f1.w);
  *(short8*)(dst + i) = o;
}

// single src->dst convert (fallback path)
__global__ __launch_bounds__(256) void convert_one(
    const float* __restrict__ src, short* __restrict__ dst) {
  size_t i = ((size_t)blockIdx.x * 256 + threadIdx.x) * 8;
  float4 f0 = *(const float4*)(src + i);
  float4 f1 = *(const float4*)(src + i + 4);
  short8 o;
  o[0] = f2bf(f0.x); o[1] = f2bf(f0.y); o[2] = f2bf(f0.z); o[3] = f2bf(f0.w);
  o[4] = f2bf(f1.x); o[5] = f2bf(f1.y); o[6] = f2bf(f1.z); o[7] = f2bf(f1.w);
  *(short8*)(dst + i) = o;
}

// ---------------------------------------------------------------------------
// bf16 GEMM core: C[m][n] = sum_k A[m][k]*B[n][k].  A [8192][1024], B [1024][1024].
// 128x128 tile, BK=64, 4 waves x (64x64). Staging via global_load_lds width=16
// with inverse-swizzled global source (chunk ^ (row&7)); linear LDS dest;
// XOR-swizzled ds_read (conflict-free). m97 2-barrier structure.
// ---------------------------------------------------------------------------
template <bool OUT_HEAD>
DI void gemm_core(const short* __restrict__ A, const short* __restrict__ B,
                  void* __restrict__ Cp, float scale, int bm, int bn) {
  __shared__ __align__(16) short sA[128 * 64];
  __shared__ __align__(16) short sB[128 * 64];

  const int tid = threadIdx.x;
  const int lane = tid & 63;
  const int wid = tid >> 6;
  const int wm = wid >> 1, wn = wid & 1;
  const int l15 = lane & 15, lq = lane >> 4;
  const int lrr = lane >> 3;  // row within 8-row group
  const int lch = lane & 7;   // 16B chunk within 128B row

  f32x4 acc[4][4] = {};

  for (int k0 = 0; k0 < 1024; k0 += 64) {
#pragma unroll
    for (int i = 0; i < 4; ++i) {
      int r0 = wid * 32 + i * 8;
      int rr = r0 + lrr;
      int sc = (lch ^ (rr & 7)) << 3;  // inverse-swizzled source chunk (shorts)
      gl16(A + (size_t)(bm + rr) * 1024 + k0 + sc, sA + r0 * 64);
      gl16(B + (size_t)(bn + rr) * 1024 + k0 + sc, sB + r0 * 64);
    }
    __syncthreads();  // drains vmcnt before barrier

#pragma unroll
    for (int ks = 0; ks < 2; ++ks) {
      short8 a[4], b[4];
#pragma unroll
      for (int mt = 0; mt < 4; ++mt) {
        int row = wm * 64 + mt * 16 + l15;
        int off = (row * 128 + ks * 64 + lq * 16) ^ ((row & 7) << 4);
        a[mt] = *(const short8*)((const char*)sA + off);
      }
#pragma unroll
      for (int nt = 0; nt < 4; ++nt) {
        int row = wn * 64 + nt * 16 + l15;
        int off = (row * 128 + ks * 64 + lq * 16) ^ ((row & 7) << 4);
        b[nt] = *(const short8*)((const char*)sB + off);
      }
#pragma unroll
      for (int mt = 0; mt < 4; ++mt)
#pragma unroll
        for (int nt = 0; nt < 4; ++nt)
          acc[mt][nt] = __builtin_amdgcn_mfma_f32_16x16x32_bf16(
              a[mt], b[nt], acc[mt][nt], 0, 0, 0);
    }
    __syncthreads();
  }

#pragma unroll
  for (int mt = 0; mt < 4; ++mt) {
#pragma unroll
    for (int nt = 0; nt < 4; ++nt) {
#pragma unroll
      for (int r = 0; r < 4; ++r) {
        int rowg = bm + wm * 64 + mt * 16 + lq * 4 + r;
        int colg = bn + wn * 64 + nt * 16 + l15;
        float val = acc[mt][nt][r] * scale;
        if (OUT_HEAD) {
          int b = rowg >> 11, s = rowg & 2047;
          int h = colg >> 6, dh = colg & 63;
          ((short*)Cp)[((size_t)(b * 16 + h) * 2048 + s) * 64 + dh] = f2bf(val);
        } else {
          ((float*)Cp)[(size_t)rowg * 1024 + colg] = val;
        }
      }
    }
  }
}

// XCD-aware tile mapping: 8 n-tiles of one A row-panel run consecutively on
// ONE XCD (id&7 = xcd under round-robin dispatch) -> A panel stays in its L2.
DI void xcd_map(int id, int& bm, int& bn) {
  int xcd = id & 7, slot = id >> 3;
  int panel = xcd + 8 * (slot >> 3);
  int ntile = slot & 7;
  bm = panel * 128;
  bn = ntile * 128;
}

__global__ __launch_bounds__(256) void proj_gemm3(
    const short* __restrict__ qb, const short* __restrict__ kb,
    const short* __restrict__ vb, const short* __restrict__ wq,
    const short* __restrict__ wk, const short* __restrict__ wv,
    short* __restrict__ xq, short* __restrict__ xk, short* __restrict__ xv) {
  int z = blockIdx.z;
  const short* A = (z == 0) ? qb : (z == 1) ? kb : vb;
  const short* B = (z == 0) ? wq : (z == 1) ? wk : wv;
  short* C = (z == 0) ? xq : (z == 1) ? xk : xv;
  float scale = (z == 0) ? 0.125f : 1.0f;
  int bm, bn;
  xcd_map(blockIdx.x, bm, bn);
  gemm_core<true>(A, B, C, scale, bm, bn);
}

__global__ __launch_bounds__(256) void proj_one(
    const short* __restrict__ A, const short* __restrict__ B,
    short* __restrict__ C, float scale) {
  int bm, bn;
  xcd_map(blockIdx.x, bm, bn);
  gemm_core<true>(A, B, C, scale, bm, bn);
}

__global__ __launch_bounds__(256) void final_gemm(
    const short* __restrict__ oa, const short* __restrict__ wo,
    float* __restrict__ out) {
  int bm, bn;
  xcd_map(blockIdx.x, bm, bn);
  gemm_core<false>(oa, wo, out, 1.0f, bm, bn);
}

// ---------------------------------------------------------------------------
// V transpose: Xv [B,H,S,64] -> XvT [B,H,64,S]. 64x64 tiles through LDS.
// ---------------------------------------------------------------------------
__global__ __launch_bounds__(256) void transpose_v(
    const short* __restrict__ Xv, short* __restrict__ XvT) {
  __shared__ __align__(16) short sT[64 * 64];
  const int tid = threadIdx.x;
  const int bh = blockIdx.y;
  const int s0 = blockIdx.x * 64;
  const short* src = Xv + ((size_t)bh * 2048 + s0) * 64;
  short* dst = XvT + (size_t)bh * 64 * 2048 + s0;
#pragma unroll
  for (int t = 0; t < 2; ++t) {
    int c = tid + t * 256;
    int r = c >> 3, c8 = (c & 7) * 8;
    short8 v = *(const short8*)(src + (size_t)r * 64 + c8);
    int off = (r * 128 + c8 * 2) ^ (((r ^ (r >> 3)) & 7) << 4);
    *(short8*)((char*)sT + off) = v;
  }
  __syncthreads();
#pragma unroll
  for (int u = 0; u < 2; ++u) {
    int c = tid + u * 256;
    int dh = c >> 3;
    int sl = (c & 7) * 8;
    short8 o;
#pragma unroll
    for (int i = 0; i < 8; ++i) {
      int r = sl + i;
      int off = (r * 128 + dh * 2) ^ (((r ^ (r >> 3)) & 7) << 4);
      o[i] = *(const short*)((const char*)sT + off);
    }
    *(short8*)(dst + (size_t)dh * 2048 + sl) = o;
  }
}

// ---------------------------------------------------------------------------
// Causal flash attention, swapped-QK^T form (unchanged from round 3).
// ---------------------------------------------------------------------------
__global__ __launch_bounds__(256) void attn_k(
    const short* __restrict__ Xq, const short* __restrict__ Xk,
    const short* __restrict__ XvT, short* __restrict__ Oa) {
  __shared__ __align__(16) short sK[64 * 64];
  __shared__ __align__(16) short sVT[64 * 64];
  __shared__ __align__(16) short sP[4][16 * 64];

  const int tid = threadIdx.x;
  const int lane = tid & 63;
  const int wid = tid >> 6;
  const int l15 = lane & 15, lq = lane >> 4;
  const int bid = blockIdx.x;
  const int ipair = bid >> 6;  // 0..15
  const int bh = bid & 63;     // same-bh blocks land on same XCD
  const int b = bh >> 4, h = bh & 15;

  const short* Q = Xq + (size_t)bh * 2048 * 64;
  const short* K = Xk + (size_t)bh * 2048 * 64;
  const short* VT = XvT + (size_t)bh * 64 * 2048;

  const int srow = tid >> 3;
  const int scol = (tid & 7) * 8;
  const int soff0 = (srow * 128 + scol * 2) ^ ((srow & 7) << 4);
  const int soff1 = ((srow + 32) * 128 + scol * 2) ^ ((srow & 7) << 4);

  short8 kreg[2], vreg[2];
  kreg[0] = *(const short8*)(K + (size_t)srow * 64 + scol);
  kreg[1] = *(const short8*)(K + (size_t)(srow + 32) * 64 + scol);
  vreg[0] = *(const short8*)(VT + (size_t)srow * 2048 + scol);
  vreg[1] = *(const short8*)(VT + (size_t)(srow + 32) * 2048 + scol);

  short* sPw = sP[wid];

  for (int seg = 0; seg < 2; ++seg) {
    const int qt = seg ? ipair : (31 - ipair);
    const int qrow0 = qt * 64 + wid * 16;
    const int qg = qrow0 + l15;

    short8 qf[2];
#pragma unroll
    for (int ks = 0; ks < 2; ++ks)
      qf[ks] = *(const short8*)(Q + (size_t)qg * 64 + ks * 32 + lq * 8);

    float m_run = -1e30f, l_run = 0.f;
    f32x4 acc[4] = {};

    for (int kt = 0; kt <= qt; ++kt) {
      const int kv0 = kt * 64;
      *(short8*)((char*)sK + soff0) = kreg[0];
      *(short8*)((char*)sK + soff1) = kreg[1];
      *(short8*)((char*)sVT + soff0) = vreg[0];
      *(short8*)((char*)sVT + soff1) = vreg[1];
      __syncthreads();

      {
        int nkt = kt + 1, nseg = seg;
        if (nkt > qt) { nseg = seg + 1; nkt = 0; }
        if (nseg < 2) {
          const int kn = nkt * 64;
          kreg[0] = *(const short8*)(K + (size_t)(kn + srow) * 64 + scol);
          kreg[1] = *(const short8*)(K + (size_t)(kn + srow + 32) * 64 + scol);
          vreg[0] = *(const short8*)(VT + (size_t)srow * 2048 + kn + scol);
          vreg[1] = *(const short8*)(VT + (size_t)(srow + 32) * 2048 + kn + scol);
        }
      }

      f32x4 sc[4] = {};
      __builtin_amdgcn_s_setprio(1);
#pragma unroll
      for (int ks = 0; ks < 2; ++ks) {
        short8 kf[4];
#pragma unroll
        for (int nt = 0; nt < 4; ++nt) {
          int row = nt * 16 + l15;
          int off = (row * 128 + ks * 64 + lq * 16) ^ ((row & 7) << 4);
          kf[nt] = *(const short8*)((const char*)sK + off);
        }
#pragma unroll
        for (int nt = 0; nt < 4; ++nt)
          sc[nt] = __builtin_amdgcn_mfma_f32_16x16x32_bf16(kf[nt], qf[ks], sc[nt], 0, 0, 0);
      }
      __builtin_amdgcn_s_setprio(0);

      float p[4][4];
      float m = -1e30f;
      const bool diag = (kt == qt);
#pragma unroll
      for (int nt = 0; nt < 4; ++nt) {
#pragma unroll
        for (int r = 0; r < 4; ++r) {
          float s = sc[nt][r];
          if (diag && (kv0 + nt * 16 + lq * 4 + r > qg)) s = -1e30f;
          p[nt][r] = s;
          m = fmaxf(m, s);
        }
      }
      m = fmaxf(m, __shfl_xor(m, 16));
      m = fmaxf(m, __shfl_xor(m, 32));

      const float m_new = fmaxf(m_run, m);
      const float corr = __expf(m_run - m_new);
      float rsum = 0.f;
#pragma unroll
      for (int nt = 0; nt < 4; ++nt)
#pragma unroll
        for (int r = 0; r < 4; ++r) {
          float e = __expf(p[nt][r] - m_new);
          p[nt][r] = e;
          rsum += e;
        }
      rsum += __shfl_xor(rsum, 16);
      rsum += __shfl_xor(rsum, 32);
      l_run = l_run * corr + rsum;
      m_run = m_new;
#pragma unroll
      for (int mt = 0; mt < 4; ++mt)
#pragma unroll
        for (int r = 0; r < 4; ++r) acc[mt][r] *= corr;

#pragma unroll
      for (int nt = 0; nt < 4; ++nt) {
        short4v pw;
#pragma unroll
        for (int r = 0; r < 4; ++r) pw[r] = f2bf(p[nt][r]);
        int off = (l15 * 128 + nt * 32 + lq * 8) ^ ((l15 & 7) << 4);
        *(short4v*)((char*)sPw + off) = pw;
      }

      __builtin_amdgcn_s_setprio(1);
#pragma unroll
      for (int ks = 0; ks < 2; ++ks) {
        int poff = (l15 * 128 + ks * 64 + lq * 16) ^ ((l15 & 7) << 4);
        short8 pf = *(const short8*)((const char*)sPw + poff);
#pragma unroll
        for (int mt = 0; mt < 4; ++mt) {
          int row = mt * 16 + l15;
          int voff = (row * 128 + ks * 64 + lq * 16) ^ ((row & 7) << 4);
          short8 vf = *(const short8*)((const char*)sVT + voff);
          acc[mt] = __builtin_amdgcn_mfma_f32_16x16x32_bf16(vf, pf, acc[mt], 0, 0, 0);
        }
      }
      __builtin_amdgcn_s_setprio(0);
      __syncthreads();
    }

    const float rl = 1.0f / l_run;
    short* orow = Oa + ((size_t)(b * 2048 + qg)) * 1024 + h * 64;
#pragma unroll
    for (int mt = 0; mt < 4; ++mt) {
      short4v o;
#pragma unroll
      for (int r = 0; r < 4; ++r) o[r] = f2bf(acc[mt][r] * rl);
      *(short4v*)(orow + mt * 16 + lq * 4) = o;
    }
  }
}

// ---------------------------------------------------------------------------
extern "C" void kernel_launch(void* const* d_in, const int* in_sizes, int n_in,
                              void* d_out, int out_size, void* d_ws,
                              size_t ws_size, hipStream_t stream) {
  const float* q = (const float*)d_in[0];
  const float* k = (const float*)d_in[1];
  const float* v = (const float*)d_in[2];
  const float* Wq = (const float*)d_in[3];
  const float* Wk = (const float*)d_in[4];
  const float* Wv = (const float*)d_in[5];
  const float* Wo = (const float*)d_in[6];

  char* ws = (char*)d_ws;
  short* wq_b = (short*)(ws + (0ull << 20));
  short* wk_b = (short*)(ws + (2ull << 20));
  short* wv_b = (short*)(ws + (4ull << 20));
  short* wo_b = (short*)(ws + (6ull << 20));
  short* xq  = (short*)(ws + (8ull << 20));    // 16 MB each, [B,H,S,Dh] bf16
  short* xk  = (short*)(ws + (24ull << 20));
  short* xv  = (short*)(ws + (40ull << 20));
  short* xvT = (short*)(ws + (56ull << 20));   // [B,H,Dh,S] bf16

  convert_w<<<dim3(1024, 1, 4), 256, 0, stream>>>(Wq, Wk, Wv, Wo, wq_b);

  if (ws_size >= (122ull << 20)) {
    short* qb = (short*)(ws + (72ull << 20));  // 16 MB each, [B*S, D] bf16
    short* kb = (short*)(ws + (88ull << 20));
    short* vb = (short*)(ws + (104ull << 20));
    short* oa = qb;  // qb dead after proj_gemm3

    convert_x<<<dim3(4096, 1, 3), 256, 0, stream>>>(q, k, v, qb, kb, vb);
    proj_gemm3<<<dim3(512, 1, 3), 256, 0, stream>>>(qb, kb, vb, wq_b, wk_b,
                                                    wv_b, xq, xk, xv);
    transpose_v<<<dim3(32, 64), 256, 0, stream>>>(xv, xvT);
    attn_k<<<dim3(1024), 256, 0, stream>>>(xq, xk, xvT, oa);
    final_gemm<<<dim3(512), 256, 0, stream>>>(oa, wo_b, (float*)d_out);
  } else {
    // ping-pong fallback: one 16 MB staging buffer, sequential per-z
    short* X = (short*)(ws + (8ull << 20));
    short* xq2 = (short*)(ws + (24ull << 20));
    short* xk2 = (short*)(ws + (40ull << 20));
    short* xv2 = (short*)(ws + (56ull << 20));
    short* xvT2 = (short*)(ws + (72ull << 20));

    convert_one<<<dim3(4096), 256, 0, stream>>>(q, X);
    proj_one<<<dim3(512), 256, 0, stream>>>(X, wq_b, xq2, 0.125f);
    convert_one<<<dim3(4096), 256, 0, stream>>>(k, X);
    proj_one<<<dim3(512), 256, 0, stream>>>(X, wk_b, xk2, 1.0f);
    convert_one<<<dim3(4096), 256, 0, stream>>>(v, X);
    proj_one<<<dim3(512), 256, 0, stream>>>(X, wv_b, xv2, 1.0f);
    transpose_v<<<dim3(32, 64), 256, 0, stream>>>(xv2, xvT2);
    attn_k<<<dim3(1024), 256, 0, stream>>>(xq2, xk2, xvT2, X);
    final_gemm<<<dim3(512), 256, 0, stream>>>(X, wo_b, (float*)d_out);
  }
}

// Round 5
// 197.810 us; speedup vs baseline: 2.3418x; 1.0133x over previous
//
#include <hip/hip_runtime.h>
#include <hip/hip_bf16.h>

#define DI __device__ __forceinline__

typedef __attribute__((ext_vector_type(8))) short short8;
typedef __attribute__((ext_vector_type(4))) short short4v;
typedef __attribute__((ext_vector_type(4))) float f32x4;

// Q pre-scale: 1/sqrt(64) * log2(e)  (exp2-domain softmax)
#define QSCALE 0.180336885f

// RNE float -> bf16 (bit trick; inputs are finite)
DI short f2bf(float f) {
  unsigned u = __builtin_bit_cast(unsigned, f);
  unsigned r = u + 0x7fffu + ((u >> 16) & 1u);
  return (short)(r >> 16);
}

// pack two f32 -> two bf16 in one u32 (lo = first arg)
DI unsigned cvt_pk(float lo, float hi) {
  unsigned r;
  asm("v_cvt_pk_bf16_f32 %0, %1, %2" : "=v"(r) : "v"(lo), "v"(hi));
  return r;
}

DI float fexp2(float x) {
#if __has_builtin(__builtin_amdgcn_exp2f)
  return __builtin_amdgcn_exp2f(x);
#else
  return exp2f(x);
#endif
}

// async global->LDS, 16B per lane. LDS dest = wave-uniform base + lane*16.
DI void gl16(const short* g, short* l) {
  __builtin_amdgcn_global_load_lds(
      (const __attribute__((address_space(1))) void*)g,
      (__attribute__((address_space(3))) void*)l, 16, 0, 0);
}

// ---------------------------------------------------------------------------
// Weight conversion: 4 x [1024x1024] fp32 -> bf16 (contiguous in ws)
// ---------------------------------------------------------------------------
__global__ __launch_bounds__(256) void convert_w(
    const float* __restrict__ wq, const float* __restrict__ wk,
    const float* __restrict__ wv, const float* __restrict__ wo,
    short* __restrict__ dst) {
  int z = blockIdx.z;
  const float* src = (z == 0) ? wq : (z == 1) ? wk : (z == 2) ? wv : wo;
  short* d = dst + (size_t)z * 1024 * 1024;
  int i = (blockIdx.x * 256 + threadIdx.x) * 4;
  float4 f = *(const float4*)(src + i);
  short4v v;
  v[0] = f2bf(f.x); v[1] = f2bf(f.y); v[2] = f2bf(f.z); v[3] = f2bf(f.w);
  *(short4v*)(d + i) = v;
}

// q/k/v fp32 -> bf16, all three in one launch (grid.z selects)
__global__ __launch_bounds__(256) void convert_x(
    const float* __restrict__ q, const float* __restrict__ k,
    const float* __restrict__ v, short* __restrict__ qb,
    short* __restrict__ kb, short* __restrict__ vb) {
  int z = blockIdx.z;
  const float* src = (z == 0) ? q : (z == 1) ? k : v;
  short* dst = (z == 0) ? qb : (z == 1) ? kb : vb;
  size_t i = ((size_t)blockIdx.x * 256 + threadIdx.x) * 8;
  float4 f0 = *(const float4*)(src + i);
  float4 f1 = *(const float4*)(src + i + 4);
  short8 o;
  o[0] = f2bf(f0.x); o[1] = f2bf(f0.y); o[2] = f2bf(f0.z); o[3] = f2bf(f0.w);
  o[4] = f2bf(f1.x); o[5] = f2bf(f1.y); o[6] = f2bf(f1.z); o[7] = f2bf(f1.w);
  *(short8*)(dst + i) = o;
}

// single src->dst convert (fallback path)
__global__ __launch_bounds__(256) void convert_one(
    const float* __restrict__ src, short* __restrict__ dst) {
  size_t i = ((size_t)blockIdx.x * 256 + threadIdx.x) * 8;
  float4 f0 = *(const float4*)(src + i);
  float4 f1 = *(const float4*)(src + i + 4);
  short8 o;
  o[0] = f2bf(f0.x); o[1] = f2bf(f0.y); o[2] = f2bf(f0.z); o[3] = f2bf(f0.w);
  o[4] = f2bf(f1.x); o[5] = f2bf(f1.y); o[6] = f2bf(f1.z); o[7] = f2bf(f1.w);
  *(short8*)(dst + i) = o;
}

// ---------------------------------------------------------------------------
// bf16 GEMM core: C[m][n] = sum_k A[m][k]*B[n][k].  A [8192][1024], B [1024][1024].
// 128x128 tile, BK=64, 4 waves x (64x64). global_load_lds width=16 staging,
// inverse-swizzled global source + linear LDS dest + XOR-swizzled ds_read.
// OMODE: 0 = fp32 row-major; 1 = bf16 [B,H,S,Dh]; 2 = bf16 [B,H,Dh,S]
// (transposed output via swapped MFMA operands -> coalesced V^T write).
// ---------------------------------------------------------------------------
enum { OUT_F32 = 0, OUT_HEAD = 1, OUT_HEADT = 2 };

template <int OMODE>
DI void gemm_core(const short* __restrict__ A, const short* __restrict__ B,
                  void* __restrict__ Cp, float scale, int bm, int bn) {
  __shared__ __align__(16) short sA[128 * 64];
  __shared__ __align__(16) short sB[128 * 64];

  const int tid = threadIdx.x;
  const int lane = tid & 63;
  const int wid = tid >> 6;
  const int wm = wid >> 1, wn = wid & 1;
  const int l15 = lane & 15, lq = lane >> 4;
  const int lrr = lane >> 3;  // row within 8-row group
  const int lch = lane & 7;   // 16B chunk within 128B row

  f32x4 acc[4][4] = {};

  for (int k0 = 0; k0 < 1024; k0 += 64) {
#pragma unroll
    for (int i = 0; i < 4; ++i) {
      int r0 = wid * 32 + i * 8;
      int rr = r0 + lrr;
      int sc = (lch ^ (rr & 7)) << 3;  // inverse-swizzled source chunk (shorts)
      gl16(A + (size_t)(bm + rr) * 1024 + k0 + sc, sA + r0 * 64);
      gl16(B + (size_t)(bn + rr) * 1024 + k0 + sc, sB + r0 * 64);
    }
    __syncthreads();  // drains vmcnt before barrier

#pragma unroll
    for (int ks = 0; ks < 2; ++ks) {
      short8 a[4], b[4];
#pragma unroll
      for (int mt = 0; mt < 4; ++mt) {
        int row = wm * 64 + mt * 16 + l15;
        int off = (row * 128 + ks * 64 + lq * 16) ^ ((row & 7) << 4);
        a[mt] = *(const short8*)((const char*)sA + off);
      }
#pragma unroll
      for (int nt = 0; nt < 4; ++nt) {
        int row = wn * 64 + nt * 16 + l15;
        int off = (row * 128 + ks * 64 + lq * 16) ^ ((row & 7) << 4);
        b[nt] = *(const short8*)((const char*)sB + off);
      }
#pragma unroll
      for (int mt = 0; mt < 4; ++mt)
#pragma unroll
        for (int nt = 0; nt < 4; ++nt) {
          if (OMODE == OUT_HEADT)
            acc[mt][nt] = __builtin_amdgcn_mfma_f32_16x16x32_bf16(
                b[nt], a[mt], acc[mt][nt], 0, 0, 0);
          else
            acc[mt][nt] = __builtin_amdgcn_mfma_f32_16x16x32_bf16(
                a[mt], b[nt], acc[mt][nt], 0, 0, 0);
        }
    }
    __syncthreads();
  }

#pragma unroll
  for (int mt = 0; mt < 4; ++mt) {
#pragma unroll
    for (int nt = 0; nt < 4; ++nt) {
#pragma unroll
      for (int r = 0; r < 4; ++r) {
        float val = acc[mt][nt][r] * scale;
        if (OMODE == OUT_HEADT) {
          // transposed tile: row = feature (n-dim), col = token (m-dim)
          int f = bn + wn * 64 + nt * 16 + lq * 4 + r;
          int t = bm + wm * 64 + mt * 16 + l15;
          int bb = t >> 11, s = t & 2047;
          int h = f >> 6, dh = f & 63;
          ((short*)Cp)[((size_t)((bb * 16 + h) * 64 + dh)) * 2048 + s] = f2bf(val);
        } else {
          int rowg = bm + wm * 64 + mt * 16 + lq * 4 + r;
          int colg = bn + wn * 64 + nt * 16 + l15;
          if (OMODE == OUT_HEAD) {
            int bb = rowg >> 11, s = rowg & 2047;
            int h = colg >> 6, dh = colg & 63;
            ((short*)Cp)[((size_t)(bb * 16 + h) * 2048 + s) * 64 + dh] = f2bf(val);
          } else {
            ((float*)Cp)[(size_t)rowg * 1024 + colg] = val;
          }
        }
      }
    }
  }
}

// XCD-aware tile mapping: 8 n-tiles of one A row-panel run consecutively on
// ONE XCD (id&7 = xcd under round-robin dispatch) -> A panel stays in its L2.
DI void xcd_map(int id, int& bm, int& bn) {
  int xcd = id & 7, slot = id >> 3;
  int panel = xcd + 8 * (slot >> 3);
  int ntile = slot & 7;
  bm = panel * 128;
  bn = ntile * 128;
}

__global__ __launch_bounds__(256) void proj_gemm3(
    const short* __restrict__ qb, const short* __restrict__ kb,
    const short* __restrict__ vb, const short* __restrict__ wq,
    const short* __restrict__ wk, const short* __restrict__ wv,
    short* __restrict__ xq, short* __restrict__ xk, short* __restrict__ xvT) {
  int z = blockIdx.z;
  int bm, bn;
  xcd_map(blockIdx.x, bm, bn);
  if (z == 0) {
    gemm_core<OUT_HEAD>(qb, wq, xq, QSCALE, bm, bn);
  } else if (z == 1) {
    gemm_core<OUT_HEAD>(kb, wk, xk, 1.0f, bm, bn);
  } else {
    gemm_core<OUT_HEADT>(vb, wv, xvT, 1.0f, bm, bn);
  }
}

__global__ __launch_bounds__(256) void proj_oneN(
    const short* __restrict__ A, const short* __restrict__ B,
    short* __restrict__ C, float scale) {
  int bm, bn;
  xcd_map(blockIdx.x, bm, bn);
  gemm_core<OUT_HEAD>(A, B, C, scale, bm, bn);
}

__global__ __launch_bounds__(256) void proj_oneT(
    const short* __restrict__ A, const short* __restrict__ B,
    short* __restrict__ C, float scale) {
  int bm, bn;
  xcd_map(blockIdx.x, bm, bn);
  gemm_core<OUT_HEADT>(A, B, C, scale, bm, bn);
}

__global__ __launch_bounds__(256) void final_gemm(
    const short* __restrict__ oa, const short* __restrict__ wo,
    float* __restrict__ out) {
  int bm, bn;
  xcd_map(blockIdx.x, bm, bn);
  gemm_core<OUT_F32>(oa, wo, out, 1.0f, bm, bn);
}

// ---------------------------------------------------------------------------
// Causal flash attention, swapped-QK^T, exp2-domain softmax, defer-max,
// cvt_pk bf16 packing. Per block: two q-tiles (i, 31-i) -> 33 KV tiles.
// ---------------------------------------------------------------------------
__global__ __launch_bounds__(256) void attn_k(
    const short* __restrict__ Xq, const short* __restrict__ Xk,
    const short* __restrict__ XvT, short* __restrict__ Oa) {
  __shared__ __align__(16) short sK[64 * 64];
  __shared__ __align__(16) short sVT[64 * 64];
  __shared__ __align__(16) short sP[4][16 * 64];

  const int tid = threadIdx.x;
  const int lane = tid & 63;
  const int wid = tid >> 6;
  const int l15 = lane & 15, lq = lane >> 4;
  const int bid = blockIdx.x;
  const int ipair = bid >> 6;  // 0..15
  const int bh = bid & 63;     // same-bh blocks land on same XCD
  const int b = bh >> 4, h = bh & 15;

  const short* Q = Xq + (size_t)bh * 2048 * 64;
  const short* K = Xk + (size_t)bh * 2048 * 64;
  const short* VT = XvT + (size_t)bh * 64 * 2048;

  const int srow = tid >> 3;
  const int scol = (tid & 7) * 8;
  const int soff0 = (srow * 128 + scol * 2) ^ ((srow & 7) << 4);
  const int soff1 = ((srow + 32) * 128 + scol * 2) ^ ((srow & 7) << 4);

  short8 kreg[2], vreg[2];
  kreg[0] = *(const short8*)(K + (size_t)srow * 64 + scol);
  kreg[1] = *(const short8*)(K + (size_t)(srow + 32) * 64 + scol);
  vreg[0] = *(const short8*)(VT + (size_t)srow * 2048 + scol);
  vreg[1] = *(const short8*)(VT + (size_t)(srow + 32) * 2048 + scol);

  short* sPw = sP[wid];

  for (int seg = 0; seg < 2; ++seg) {
    const int qt = seg ? ipair : (31 - ipair);
    const int qrow0 = qt * 64 + wid * 16;
    const int qg = qrow0 + l15;

    short8 qf[2];
#pragma unroll
    for (int ks = 0; ks < 2; ++ks)
      qf[ks] = *(const short8*)(Q + (size_t)qg * 64 + ks * 32 + lq * 8);

    float m_run = -1e30f, l_run = 0.f;
    f32x4 acc[4] = {};

    for (int kt = 0; kt <= qt; ++kt) {
      const int kv0 = kt * 64;
      *(short8*)((char*)sK + soff0) = kreg[0];
      *(short8*)((char*)sK + soff1) = kreg[1];
      *(short8*)((char*)sVT + soff0) = vreg[0];
      *(short8*)((char*)sVT + soff1) = vreg[1];
      __syncthreads();

      {
        int nkt = kt + 1, nseg = seg;
        if (nkt > qt) { nseg = seg + 1; nkt = 0; }
        if (nseg < 2) {
          const int kn = nkt * 64;
          kreg[0] = *(const short8*)(K + (size_t)(kn + srow) * 64 + scol);
          kreg[1] = *(const short8*)(K + (size_t)(kn + srow + 32) * 64 + scol);
          vreg[0] = *(const short8*)(VT + (size_t)srow * 2048 + kn + scol);
          vreg[1] = *(const short8*)(VT + (size_t)(srow + 32) * 2048 + kn + scol);
        }
      }

      f32x4 sc[4] = {};
      __builtin_amdgcn_s_setprio(1);
#pragma unroll
      for (int ks = 0; ks < 2; ++ks) {
        short8 kf[4];
#pragma unroll
        for (int nt = 0; nt < 4; ++nt) {
          int row = nt * 16 + l15;
          int off = (row * 128 + ks * 64 + lq * 16) ^ ((row & 7) << 4);
          kf[nt] = *(const short8*)((const char*)sK + off);
        }
#pragma unroll
        for (int nt = 0; nt < 4; ++nt)
          sc[nt] = __builtin_amdgcn_mfma_f32_16x16x32_bf16(kf[nt], qf[ks], sc[nt], 0, 0, 0);
      }
      __builtin_amdgcn_s_setprio(0);

      // ---- mask + tile max (scores already in log2 units) ----
      float p[4][4];
      float m = -1e30f;
      const bool diag = (kt == qt);
#pragma unroll
      for (int nt = 0; nt < 4; ++nt) {
#pragma unroll
        for (int r = 0; r < 4; ++r) {
          float s = sc[nt][r];
          if (diag && (kv0 + nt * 16 + lq * 4 + r > qg)) s = -1e30f;
          p[nt][r] = s;
          m = fmaxf(m, s);
        }
      }
      m = fmaxf(m, __shfl_xor(m, 16));
      m = fmaxf(m, __shfl_xor(m, 32));

      // ---- T13 defer-max: rescale only when max grows past THR=8 ----
      if (!__all(m - m_run <= 8.0f)) {
        const float m_new = fmaxf(m_run, m);
        const float corr = fexp2(m_run - m_new);
        l_run *= corr;
#pragma unroll
        for (int mt = 0; mt < 4; ++mt)
#pragma unroll
          for (int r = 0; r < 4; ++r) acc[mt][r] *= corr;
        m_run = m_new;
      }

      float rsum = 0.f;
#pragma unroll
      for (int nt = 0; nt < 4; ++nt)
#pragma unroll
        for (int r = 0; r < 4; ++r) {
          float e = fexp2(p[nt][r] - m_run);
          p[nt][r] = e;
          rsum += e;
        }
      rsum += __shfl_xor(rsum, 16);
      rsum += __shfl_xor(rsum, 32);
      l_run += rsum;

      // ---- P -> per-wave LDS, packed via v_cvt_pk_bf16_f32 ----
#pragma unroll
      for (int nt = 0; nt < 4; ++nt) {
        uint2 pw;
        pw.x = cvt_pk(p[nt][0], p[nt][1]);
        pw.y = cvt_pk(p[nt][2], p[nt][3]);
        int off = (l15 * 128 + nt * 32 + lq * 8) ^ ((l15 & 7) << 4);
        *(uint2*)((char*)sPw + off) = pw;
      }

      // ---- PV: O^T[dh][q] += V^T[dh][key] * P^T[key][q] ----
      __builtin_amdgcn_s_setprio(1);
#pragma unroll
      for (int ks = 0; ks < 2; ++ks) {
        int poff = (l15 * 128 + ks * 64 + lq * 16) ^ ((l15 & 7) << 4);
        short8 pf = *(const short8*)((const char*)sPw + poff);
#pragma unroll
        for (int mt = 0; mt < 4; ++mt) {
          int row = mt * 16 + l15;
          int voff = (row * 128 + ks * 64 + lq * 16) ^ ((row & 7) << 4);
          short8 vf = *(const short8*)((const char*)sVT + voff);
          acc[mt] = __builtin_amdgcn_mfma_f32_16x16x32_bf16(vf, pf, acc[mt], 0, 0, 0);
        }
      }
      __builtin_amdgcn_s_setprio(0);
      __syncthreads();
    }

    const float rl = 1.0f / l_run;
    short* orow = Oa + ((size_t)(b * 2048 + qg)) * 1024 + h * 64;
#pragma unroll
    for (int mt = 0; mt < 4; ++mt) {
      uint2 o;
      o.x = cvt_pk(acc[mt][0] * rl, acc[mt][1] * rl);
      o.y = cvt_pk(acc[mt][2] * rl, acc[mt][3] * rl);
      *(uint2*)(orow + mt * 16 + lq * 4) = o;
    }
  }
}

// ---------------------------------------------------------------------------
extern "C" void kernel_launch(void* const* d_in, const int* in_sizes, int n_in,
                              void* d_out, int out_size, void* d_ws,
                              size_t ws_size, hipStream_t stream) {
  const float* q = (const float*)d_in[0];
  const float* k = (const float*)d_in[1];
  const float* v = (const float*)d_in[2];
  const float* Wq = (const float*)d_in[3];
  const float* Wk = (const float*)d_in[4];
  const float* Wv = (const float*)d_in[5];
  const float* Wo = (const float*)d_in[6];

  char* ws = (char*)d_ws;
  short* wq_b = (short*)(ws + (0ull << 20));
  short* wk_b = (short*)(ws + (2ull << 20));
  short* wv_b = (short*)(ws + (4ull << 20));
  short* wo_b = (short*)(ws + (6ull << 20));
  short* xq  = (short*)(ws + (8ull << 20));    // 16 MB each, [B,H,S,Dh] bf16
  short* xk  = (short*)(ws + (24ull << 20));
  short* xvT = (short*)(ws + (56ull << 20));   // [B,H,Dh,S] bf16

  convert_w<<<dim3(1024, 1, 4), 256, 0, stream>>>(Wq, Wk, Wv, Wo, wq_b);

  if (ws_size >= (122ull << 20)) {
    short* qb = (short*)(ws + (72ull << 20));  // 16 MB each, [B*S, D] bf16
    short* kb = (short*)(ws + (88ull << 20));
    short* vb = (short*)(ws + (104ull << 20));
    short* oa = qb;  // qb dead after proj_gemm3

    convert_x<<<dim3(4096, 1, 3), 256, 0, stream>>>(q, k, v, qb, kb, vb);
    proj_gemm3<<<dim3(512, 1, 3), 256, 0, stream>>>(qb, kb, vb, wq_b, wk_b,
                                                    wv_b, xq, xk, xvT);
    attn_k<<<dim3(1024), 256, 0, stream>>>(xq, xk, xvT, oa);
    final_gemm<<<dim3(512), 256, 0, stream>>>(oa, wo_b, (float*)d_out);
  } else {
    // ping-pong fallback: one 16 MB staging buffer, sequential per-z
    short* X = (short*)(ws + (8ull << 20));
    short* xq2 = (short*)(ws + (24ull << 20));
    short* xk2 = (short*)(ws + (40ull << 20));
    short* xvT2 = (short*)(ws + (56ull << 20));
    short* oa2 = (short*)(ws + (72ull << 20));

    convert_one<<<dim3(4096), 256, 0, stream>>>(q, X);
    proj_oneN<<<dim3(512), 256, 0, stream>>>(X, wq_b, xq2, QSCALE);
    convert_one<<<dim3(4096), 256, 0, stream>>>(k, X);
    proj_oneN<<<dim3(512), 256, 0, stream>>>(X, wk_b, xk2, 1.0f);
    convert_one<<<dim3(4096), 256, 0, stream>>>(v, X);
    proj_oneT<<<dim3(512), 256, 0, stream>>>(X, wv_b, xvT2, 1.0f);
    attn_k<<<dim3(1024), 256, 0, stream>>>(xq2, xk2, xvT2, oa2);
    final_gemm<<<dim3(512), 256, 0, stream>>>(oa2, wo_b, (float*)d_out);
  }
}

// Round 6
// 184.573 us; speedup vs baseline: 2.5097x; 1.0717x over previous
//
#include <hip/hip_runtime.h>
#include <hip/hip_bf16.h>

#define DI __device__ __forceinline__

typedef __attribute__((ext_vector_type(8))) short short8;
typedef __attribute__((ext_vector_type(4))) short short4v;
typedef __attribute__((ext_vector_type(4))) float f32x4;

// Q pre-scale: 1/sqrt(64) * log2(e)  (exp2-domain softmax)
#define QSCALE 0.180336885f

// RNE float -> bf16 (bit trick; inputs are finite)
DI short f2bf(float f) {
  unsigned u = __builtin_bit_cast(unsigned, f);
  unsigned r = u + 0x7fffu + ((u >> 16) & 1u);
  return (short)(r >> 16);
}

DI float fexp2(float x) {
#if __has_builtin(__builtin_amdgcn_exp2f)
  return __builtin_amdgcn_exp2f(x);
#else
  return exp2f(x);
#endif
}

// async global->LDS, 16B per lane. LDS dest = wave-uniform base + lane*16.
DI void gl16(const short* g, short* l) {
  __builtin_amdgcn_global_load_lds(
      (const __attribute__((address_space(1))) void*)g,
      (__attribute__((address_space(3))) void*)l, 16, 0, 0);
}

// ---------------------------------------------------------------------------
// Weight conversion: 4 x [1024x1024] fp32 -> bf16 (contiguous in ws)
// ---------------------------------------------------------------------------
__global__ __launch_bounds__(256) void convert_w(
    const float* __restrict__ wq, const float* __restrict__ wk,
    const float* __restrict__ wv, const float* __restrict__ wo,
    short* __restrict__ dst) {
  int z = blockIdx.z;
  const float* src = (z == 0) ? wq : (z == 1) ? wk : (z == 2) ? wv : wo;
  short* d = dst + (size_t)z * 1024 * 1024;
  int i = (blockIdx.x * 256 + threadIdx.x) * 4;
  float4 f = *(const float4*)(src + i);
  short4v v;
  v[0] = f2bf(f.x); v[1] = f2bf(f.y); v[2] = f2bf(f.z); v[3] = f2bf(f.w);
  *(short4v*)(d + i) = v;
}

// q/k/v fp32 -> bf16, all three in one launch (grid.z selects)
__global__ __launch_bounds__(256) void convert_x(
    const float* __restrict__ q, const float* __restrict__ k,
    const float* __restrict__ v, short* __restrict__ qb,
    short* __restrict__ kb, short* __restrict__ vb) {
  int z = blockIdx.z;
  const float* src = (z == 0) ? q : (z == 1) ? k : v;
  short* dst = (z == 0) ? qb : (z == 1) ? kb : vb;
  size_t i = ((size_t)blockIdx.x * 256 + threadIdx.x) * 8;
  float4 f0 = *(const float4*)(src + i);
  float4 f1 = *(const float4*)(src + i + 4);
  short8 o;
  o[0] = f2bf(f0.x); o[1] = f2bf(f0.y); o[2] = f2bf(f0.z); o[3] = f2bf(f0.w);
  o[4] = f2bf(f1.x); o[5] = f2bf(f1.y); o[6] = f2bf(f1.z); o[7] = f2bf(f1.w);
  *(short8*)(dst + i) = o;
}

// single src->dst convert (fallback path)
__global__ __launch_bounds__(256) void convert_one(
    const float* __restrict__ src, short* __restrict__ dst) {
  size_t i = ((size_t)blockIdx.x * 256 + threadIdx.x) * 8;
  float4 f0 = *(const float4*)(src + i);
  float4 f1 = *(const float4*)(src + i + 4);
  short8 o;
  o[0] = f2bf(f0.x); o[1] = f2bf(f0.y); o[2] = f2bf(f0.z); o[3] = f2bf(f0.w);
  o[4] = f2bf(f1.x); o[5] = f2bf(f1.y); o[6] = f2bf(f1.z); o[7] = f2bf(f1.w);
  *(short8*)(dst + i) = o;
}

// ---------------------------------------------------------------------------
// bf16 GEMM core: C[m][n] = sum_k A[m][k]*B[n][k].  A [8192][1024], B [1024][1024].
// 128x128 tile, BK=64, 4 waves x (64x64). global_load_lds width=16 staging,
// inverse-swizzled global source + linear LDS dest + XOR-swizzled ds_read.
// OMODE: 0 = fp32 row-major; 1 = bf16 [B,H,S,Dh]; 2 = bf16 [B,H,Dh,S]
// (transposed output via swapped MFMA operands -> coalesced V^T write).
// ---------------------------------------------------------------------------
enum { OUT_F32 = 0, OUT_HEAD = 1, OUT_HEADT = 2 };

template <int OMODE>
DI void gemm_core(const short* __restrict__ A, const short* __restrict__ B,
                  void* __restrict__ Cp, float scale, int bm, int bn) {
  __shared__ __align__(16) short sA[128 * 64];
  __shared__ __align__(16) short sB[128 * 64];

  const int tid = threadIdx.x;
  const int lane = tid & 63;
  const int wid = tid >> 6;
  const int wm = wid >> 1, wn = wid & 1;
  const int l15 = lane & 15, lq = lane >> 4;
  const int lrr = lane >> 3;  // row within 8-row group
  const int lch = lane & 7;   // 16B chunk within 128B row

  f32x4 acc[4][4] = {};

  for (int k0 = 0; k0 < 1024; k0 += 64) {
#pragma unroll
    for (int i = 0; i < 4; ++i) {
      int r0 = wid * 32 + i * 8;
      int rr = r0 + lrr;
      int sc = (lch ^ (rr & 7)) << 3;  // inverse-swizzled source chunk (shorts)
      gl16(A + (size_t)(bm + rr) * 1024 + k0 + sc, sA + r0 * 64);
      gl16(B + (size_t)(bn + rr) * 1024 + k0 + sc, sB + r0 * 64);
    }
    __syncthreads();  // drains vmcnt before barrier

#pragma unroll
    for (int ks = 0; ks < 2; ++ks) {
      short8 a[4], b[4];
#pragma unroll
      for (int mt = 0; mt < 4; ++mt) {
        int row = wm * 64 + mt * 16 + l15;
        int off = (row * 128 + ks * 64 + lq * 16) ^ ((row & 7) << 4);
        a[mt] = *(const short8*)((const char*)sA + off);
      }
#pragma unroll
      for (int nt = 0; nt < 4; ++nt) {
        int row = wn * 64 + nt * 16 + l15;
        int off = (row * 128 + ks * 64 + lq * 16) ^ ((row & 7) << 4);
        b[nt] = *(const short8*)((const char*)sB + off);
      }
#pragma unroll
      for (int mt = 0; mt < 4; ++mt)
#pragma unroll
        for (int nt = 0; nt < 4; ++nt) {
          if (OMODE == OUT_HEADT)
            acc[mt][nt] = __builtin_amdgcn_mfma_f32_16x16x32_bf16(
                b[nt], a[mt], acc[mt][nt], 0, 0, 0);
          else
            acc[mt][nt] = __builtin_amdgcn_mfma_f32_16x16x32_bf16(
                a[mt], b[nt], acc[mt][nt], 0, 0, 0);
        }
    }
    __syncthreads();
  }

#pragma unroll
  for (int mt = 0; mt < 4; ++mt) {
#pragma unroll
    for (int nt = 0; nt < 4; ++nt) {
#pragma unroll
      for (int r = 0; r < 4; ++r) {
        float val = acc[mt][nt][r] * scale;
        if (OMODE == OUT_HEADT) {
          // transposed tile: row = feature (n-dim), col = token (m-dim)
          int f = bn + wn * 64 + nt * 16 + lq * 4 + r;
          int t = bm + wm * 64 + mt * 16 + l15;
          int bb = t >> 11, s = t & 2047;
          int h = f >> 6, dh = f & 63;
          ((short*)Cp)[((size_t)((bb * 16 + h) * 64 + dh)) * 2048 + s] = f2bf(val);
        } else {
          int rowg = bm + wm * 64 + mt * 16 + lq * 4 + r;
          int colg = bn + wn * 64 + nt * 16 + l15;
          if (OMODE == OUT_HEAD) {
            int bb = rowg >> 11, s = rowg & 2047;
            int h = colg >> 6, dh = colg & 63;
            ((short*)Cp)[((size_t)(bb * 16 + h) * 2048 + s) * 64 + dh] = f2bf(val);
          } else {
            ((float*)Cp)[(size_t)rowg * 1024 + colg] = val;
          }
        }
      }
    }
  }
}

// XCD-aware tile mapping: 8 n-tiles of one A row-panel run consecutively on
// ONE XCD (id&7 = xcd under round-robin dispatch) -> A panel stays in its L2.
DI void xcd_map(int id, int& bm, int& bn) {
  int xcd = id & 7, slot = id >> 3;
  int panel = xcd + 8 * (slot >> 3);
  int ntile = slot & 7;
  bm = panel * 128;
  bn = ntile * 128;
}

__global__ __launch_bounds__(256) void proj_gemm3(
    const short* __restrict__ qb, const short* __restrict__ kb,
    const short* __restrict__ vb, const short* __restrict__ wq,
    const short* __restrict__ wk, const short* __restrict__ wv,
    short* __restrict__ xq, short* __restrict__ xk, short* __restrict__ xvT) {
  int z = blockIdx.z;
  int bm, bn;
  xcd_map(blockIdx.x, bm, bn);
  if (z == 0) {
    gemm_core<OUT_HEAD>(qb, wq, xq, QSCALE, bm, bn);
  } else if (z == 1) {
    gemm_core<OUT_HEAD>(kb, wk, xk, 1.0f, bm, bn);
  } else {
    gemm_core<OUT_HEADT>(vb, wv, xvT, 1.0f, bm, bn);
  }
}

__global__ __launch_bounds__(256) void proj_oneN(
    const short* __restrict__ A, const short* __restrict__ B,
    short* __restrict__ C, float scale) {
  int bm, bn;
  xcd_map(blockIdx.x, bm, bn);
  gemm_core<OUT_HEAD>(A, B, C, scale, bm, bn);
}

__global__ __launch_bounds__(256) void proj_oneT(
    const short* __restrict__ A, const short* __restrict__ B,
    short* __restrict__ C, float scale) {
  int bm, bn;
  xcd_map(blockIdx.x, bm, bn);
  gemm_core<OUT_HEADT>(A, B, C, scale, bm, bn);
}

__global__ __launch_bounds__(256) void final_gemm(
    const short* __restrict__ oa, const short* __restrict__ wo,
    float* __restrict__ out) {
  int bm, bn;
  xcd_map(blockIdx.x, bm, bn);
  gemm_core<OUT_F32>(oa, wo, out, 1.0f, bm, bn);
}

// ---------------------------------------------------------------------------
// Causal flash attention, swapped-QK^T, exp2-domain softmax, defer-max.
// Double-buffered K/V^T LDS -> ONE barrier per KV tile: compute from buf[p]
// while next tile's regs are loaded (T14) and written to buf[p^1] at iter end.
// Per block: two q-tiles (i, 31-i) -> 33 KV tiles, perfect balance.
// LDS = 2*16KB (K,VT dbuf) + 8KB (P) = 40KB -> 4 blocks/CU.
// ---------------------------------------------------------------------------
__global__ __launch_bounds__(256, 4) void attn_k(
    const short* __restrict__ Xq, const short* __restrict__ Xk,
    const short* __restrict__ XvT, short* __restrict__ Oa) {
  __shared__ __align__(16) short sK[2][64 * 64];
  __shared__ __align__(16) short sVT[2][64 * 64];
  __shared__ __align__(16) short sP[4][16 * 64];

  const int tid = threadIdx.x;
  const int lane = tid & 63;
  const int wid = tid >> 6;
  const int l15 = lane & 15, lq = lane >> 4;
  const int bid = blockIdx.x;
  const int ipair = bid >> 6;  // 0..15
  const int bh = bid & 63;     // same-bh blocks land on same XCD
  const int b = bh >> 4, h = bh & 15;

  const short* Q = Xq + (size_t)bh * 2048 * 64;
  const short* K = Xk + (size_t)bh * 2048 * 64;
  const short* VT = XvT + (size_t)bh * 64 * 2048;

  const int srow = tid >> 3;
  const int scol = (tid & 7) * 8;
  const int soff0 = (srow * 128 + scol * 2) ^ ((srow & 7) << 4);
  const int soff1 = ((srow + 32) * 128 + scol * 2) ^ ((srow & 7) << 4);

  short8 kreg[2], vreg[2];
  kreg[0] = *(const short8*)(K + (size_t)srow * 64 + scol);
  kreg[1] = *(const short8*)(K + (size_t)(srow + 32) * 64 + scol);
  vreg[0] = *(const short8*)(VT + (size_t)srow * 2048 + scol);
  vreg[1] = *(const short8*)(VT + (size_t)(srow + 32) * 2048 + scol);

  // prologue: tile 0 -> buffer 0 (first-iter barrier publishes it)
  *(short8*)((char*)sK[0] + soff0) = kreg[0];
  *(short8*)((char*)sK[0] + soff1) = kreg[1];
  *(short8*)((char*)sVT[0] + soff0) = vreg[0];
  *(short8*)((char*)sVT[0] + soff1) = vreg[1];

  short* sPw = sP[wid];
  int p = 0;

  for (int seg = 0; seg < 2; ++seg) {
    const int qt = seg ? ipair : (31 - ipair);
    const int qrow0 = qt * 64 + wid * 16;
    const int qg = qrow0 + l15;

    short8 qf[2];
#pragma unroll
    for (int ks = 0; ks < 2; ++ks)
      qf[ks] = *(const short8*)(Q + (size_t)qg * 64 + ks * 32 + lq * 8);

    float m_run = -1e30f, l_run = 0.f;
    f32x4 acc[4] = {};

    for (int kt = 0; kt <= qt; ++kt) {
      const int kv0 = kt * 64;
      __syncthreads();  // buf[p] ready for all waves

      // ---- T14: issue next tile's global loads (land during compute) ----
      int nkt = kt + 1, nseg = seg;
      if (nkt > qt) { nseg = seg + 1; nkt = 0; }
      const bool hn = (nseg < 2);
      if (hn) {
        const int kn = nkt * 64;
        kreg[0] = *(const short8*)(K + (size_t)(kn + srow) * 64 + scol);
        kreg[1] = *(const short8*)(K + (size_t)(kn + srow + 32) * 64 + scol);
        vreg[0] = *(const short8*)(VT + (size_t)srow * 2048 + kn + scol);
        vreg[1] = *(const short8*)(VT + (size_t)(srow + 32) * 2048 + kn + scol);
      }

      const char* bufK = (const char*)sK[p];
      const char* bufV = (const char*)sVT[p];

      // ---- QK^T swapped: sc[nt][r] = S[key=kv0+nt*16+lq*4+r][q=l15] ----
      f32x4 sc[4] = {};
      __builtin_amdgcn_s_setprio(1);
#pragma unroll
      for (int ks = 0; ks < 2; ++ks) {
        short8 kf[4];
#pragma unroll
        for (int nt = 0; nt < 4; ++nt) {
          int row = nt * 16 + l15;
          int off = (row * 128 + ks * 64 + lq * 16) ^ ((row & 7) << 4);
          kf[nt] = *(const short8*)(bufK + off);
        }
#pragma unroll
        for (int nt = 0; nt < 4; ++nt)
          sc[nt] = __builtin_amdgcn_mfma_f32_16x16x32_bf16(kf[nt], qf[ks], sc[nt], 0, 0, 0);
      }
      __builtin_amdgcn_s_setprio(0);

      // ---- mask + tile max (scores already in log2 units) ----
      float pv[4][4];
      float m = -1e30f;
      const bool diag = (kt == qt);
#pragma unroll
      for (int nt = 0; nt < 4; ++nt) {
#pragma unroll
        for (int r = 0; r < 4; ++r) {
          float s = sc[nt][r];
          if (diag && (kv0 + nt * 16 + lq * 4 + r > qg)) s = -1e30f;
          pv[nt][r] = s;
          m = fmaxf(m, s);
        }
      }
      m = fmaxf(m, __shfl_xor(m, 16));
      m = fmaxf(m, __shfl_xor(m, 32));

      // ---- T13 defer-max: rescale only when max grows past THR=8 ----
      if (!__all(m - m_run <= 8.0f)) {
        const float m_new = fmaxf(m_run, m);
        const float corr = fexp2(m_run - m_new);
        l_run *= corr;
#pragma unroll
        for (int mt = 0; mt < 4; ++mt)
#pragma unroll
          for (int r = 0; r < 4; ++r) acc[mt][r] *= corr;
        m_run = m_new;
      }

      float rsum = 0.f;
#pragma unroll
      for (int nt = 0; nt < 4; ++nt)
#pragma unroll
        for (int r = 0; r < 4; ++r) {
          float e = fexp2(pv[nt][r] - m_run);
          pv[nt][r] = e;
          rsum += e;
        }
      rsum += __shfl_xor(rsum, 16);
      rsum += __shfl_xor(rsum, 32);
      l_run += rsum;

      // ---- P -> per-wave LDS [q][key], vectorized ds_write_b64 ----
#pragma unroll
      for (int nt = 0; nt < 4; ++nt) {
        short4v pw;
#pragma unroll
        for (int r = 0; r < 4; ++r) pw[r] = f2bf(pv[nt][r]);
        int off = (l15 * 128 + nt * 32 + lq * 8) ^ ((l15 & 7) << 4);
        *(short4v*)((char*)sPw + off) = pw;
      }

      // ---- PV: O^T[dh][q] += V^T[dh][key] * P^T[key][q] ----
      __builtin_amdgcn_s_setprio(1);
#pragma unroll
      for (int ks = 0; ks < 2; ++ks) {
        int poff = (l15 * 128 + ks * 64 + lq * 16) ^ ((l15 & 7) << 4);
        short8 pf = *(const short8*)((const char*)sPw + poff);
#pragma unroll
        for (int mt = 0; mt < 4; ++mt) {
          int row = mt * 16 + l15;
          int voff = (row * 128 + ks * 64 + lq * 16) ^ ((row & 7) << 4);
          short8 vf = *(const short8*)(bufV + voff);
          acc[mt] = __builtin_amdgcn_mfma_f32_16x16x32_bf16(vf, pf, acc[mt], 0, 0, 0);
        }
      }
      __builtin_amdgcn_s_setprio(0);

      // ---- write next tile into buf[p^1] (published by next barrier) ----
      if (hn) {
        *(short8*)((char*)sK[p ^ 1] + soff0) = kreg[0];
        *(short8*)((char*)sK[p ^ 1] + soff1) = kreg[1];
        *(short8*)((char*)sVT[p ^ 1] + soff0) = vreg[0];
        *(short8*)((char*)sVT[p ^ 1] + soff1) = vreg[1];
      }
      p ^= 1;
    }

    // ---- epilogue: O[q][dh] = acc^T / l, packed 8B stores ----
    const float rl = 1.0f / l_run;
    short* orow = Oa + ((size_t)(b * 2048 + qg)) * 1024 + h * 64;
#pragma unroll
    for (int mt = 0; mt < 4; ++mt) {
      short4v o;
#pragma unroll
      for (int r = 0; r < 4; ++r) o[r] = f2bf(acc[mt][r] * rl);
      *(short4v*)(orow + mt * 16 + lq * 4) = o;
    }
  }
}

// ---------------------------------------------------------------------------
extern "C" void kernel_launch(void* const* d_in, const int* in_sizes, int n_in,
                              void* d_out, int out_size, void* d_ws,
                              size_t ws_size, hipStream_t stream) {
  const float* q = (const float*)d_in[0];
  const float* k = (const float*)d_in[1];
  const float* v = (const float*)d_in[2];
  const float* Wq = (const float*)d_in[3];
  const float* Wk = (const float*)d_in[4];
  const float* Wv = (const float*)d_in[5];
  const float* Wo = (const float*)d_in[6];

  char* ws = (char*)d_ws;
  short* wq_b = (short*)(ws + (0ull << 20));
  short* wk_b = (short*)(ws + (2ull << 20));
  short* wv_b = (short*)(ws + (4ull << 20));
  short* wo_b = (short*)(ws + (6ull << 20));
  short* xq  = (short*)(ws + (8ull << 20));    // 16 MB each, [B,H,S,Dh] bf16
  short* xk  = (short*)(ws + (24ull << 20));
  short* xvT = (short*)(ws + (56ull << 20));   // [B,H,Dh,S] bf16

  convert_w<<<dim3(1024, 1, 4), 256, 0, stream>>>(Wq, Wk, Wv, Wo, wq_b);

  if (ws_size >= (122ull << 20)) {
    short* qb = (short*)(ws + (72ull << 20));  // 16 MB each, [B*S, D] bf16
    short* kb = (short*)(ws + (88ull << 20));
    short* vb = (short*)(ws + (104ull << 20));
    short* oa = qb;  // qb dead after proj_gemm3

    convert_x<<<dim3(4096, 1, 3), 256, 0, stream>>>(q, k, v, qb, kb, vb);
    proj_gemm3<<<dim3(512, 1, 3), 256, 0, stream>>>(qb, kb, vb, wq_b, wk_b,
                                                    wv_b, xq, xk, xvT);
    attn_k<<<dim3(1024), 256, 0, stream>>>(xq, xk, xvT, oa);
    final_gemm<<<dim3(512), 256, 0, stream>>>(oa, wo_b, (float*)d_out);
  } else {
    // ping-pong fallback: one 16 MB staging buffer, sequential per-z
    short* X = (short*)(ws + (8ull << 20));
    short* xq2 = (short*)(ws + (24ull << 20));
    short* xk2 = (short*)(ws + (40ull << 20));
    short* xvT2 = (short*)(ws + (56ull << 20));
    short* oa2 = (short*)(ws + (72ull << 20));

    convert_one<<<dim3(4096), 256, 0, stream>>>(q, X);
    proj_oneN<<<dim3(512), 256, 0, stream>>>(X, wq_b, xq2, QSCALE);
    convert_one<<<dim3(4096), 256, 0, stream>>>(k, X);
    proj_oneN<<<dim3(512), 256, 0, stream>>>(X, wk_b, xk2, 1.0f);
    convert_one<<<dim3(4096), 256, 0, stream>>>(v, X);
    proj_oneT<<<dim3(512), 256, 0, stream>>>(X, wv_b, xvT2, 1.0f);
    attn_k<<<dim3(1024), 256, 0, stream>>>(xq2, xk2, xvT2, oa2);
    final_gemm<<<dim3(512), 256, 0, stream>>>(oa2, wo_b, (float*)d_out);
  }
}

// Round 8
// 178.158 us; speedup vs baseline: 2.6001x; 1.0360x over previous
//
#include <hip/hip_runtime.h>
#include <hip/hip_bf16.h>

#define DI __device__ __forceinline__

typedef __attribute__((ext_vector_type(8))) short short8;
typedef __attribute__((ext_vector_type(4))) short short4v;
typedef __attribute__((ext_vector_type(4))) float f32x4;

// Q pre-scale: 1/sqrt(64) * log2(e)  (exp2-domain softmax)
#define QSCALE 0.180336885f

// RNE float -> bf16 via native fptrunc (compiler packs v_cvt_pk_bf16_f32)
DI short f2bf(float f) {
  __hip_bfloat16 h = __float2bfloat16(f);
  return __builtin_bit_cast(short, h);
}

DI float fexp2(float x) {
#if __has_builtin(__builtin_amdgcn_exp2f)
  return __builtin_amdgcn_exp2f(x);
#else
  return exp2f(x);
#endif
}

// async global->LDS, 16B per lane. LDS dest = wave-uniform base + lane*16.
DI void gl16(const short* g, short* l) {
  __builtin_amdgcn_global_load_lds(
      (const __attribute__((address_space(1))) void*)g,
      (__attribute__((address_space(3))) void*)l, 16, 0, 0);
}

// ---------------------------------------------------------------------------
// Weight conversion: 4 x [1024x1024] fp32 -> bf16 (contiguous in ws)
// ---------------------------------------------------------------------------
__global__ __launch_bounds__(256) void convert_w(
    const float* __restrict__ wq, const float* __restrict__ wk,
    const float* __restrict__ wv, const float* __restrict__ wo,
    short* __restrict__ dst) {
  int z = blockIdx.z;
  const float* src = (z == 0) ? wq : (z == 1) ? wk : (z == 2) ? wv : wo;
  short* d = dst + (size_t)z * 1024 * 1024;
  int i = (blockIdx.x * 256 + threadIdx.x) * 4;
  float4 f = *(const float4*)(src + i);
  short4v v;
  v[0] = f2bf(f.x); v[1] = f2bf(f.y); v[2] = f2bf(f.z); v[3] = f2bf(f.w);
  *(short4v*)(d + i) = v;
}

// q/k/v fp32 -> bf16, all three in one launch (grid.z selects)
__global__ __launch_bounds__(256) void convert_x(
    const float* __restrict__ q, const float* __restrict__ k,
    const float* __restrict__ v, short* __restrict__ qb,
    short* __restrict__ kb, short* __restrict__ vb) {
  int z = blockIdx.z;
  const float* src = (z == 0) ? q : (z == 1) ? k : v;
  short* dst = (z == 0) ? qb : (z == 1) ? kb : vb;
  size_t i = ((size_t)blockIdx.x * 256 + threadIdx.x) * 8;
  float4 f0 = *(const float4*)(src + i);
  float4 f1 = *(const float4*)(src + i + 4);
  short8 o;
  o[0] = f2bf(f0.x); o[1] = f2bf(f0.y); o[2] = f2bf(f0.z); o[3] = f2bf(f0.w);
  o[4] = f2bf(f1.x); o[5] = f2bf(f1.y); o[6] = f2bf(f1.z); o[7] = f2bf(f1.w);
  *(short8*)(dst + i) = o;
}

// single src->dst convert (fallback path)
__global__ __launch_bounds__(256) void convert_one(
    const float* __restrict__ src, short* __restrict__ dst) {
  size_t i = ((size_t)blockIdx.x * 256 + threadIdx.x) * 8;
  float4 f0 = *(const float4*)(src + i);
  float4 f1 = *(const float4*)(src + i + 4);
  short8 o;
  o[0] = f2bf(f0.x); o[1] = f2bf(f0.y); o[2] = f2bf(f0.z); o[3] = f2bf(f0.w);
  o[4] = f2bf(f1.x); o[5] = f2bf(f1.y); o[6] = f2bf(f1.z); o[7] = f2bf(f1.w);
  *(short8*)(dst + i) = o;
}

// ---------------------------------------------------------------------------
// bf16 GEMM core: C[m][n] = sum_k A[m][k]*B[n][k].  A [8192][1024], B [1024][1024].
// 128x128 tile, BK=64, 4 waves x (64x64). global_load_lds width=16 staging,
// inverse-swizzled global source + linear LDS dest + XOR-swizzled ds_read.
// OMODE: 0 = fp32 row-major; 1 = bf16 [B,H,S,Dh]; 2 = bf16 [B,H,Dh,S]
// ---------------------------------------------------------------------------
enum { OUT_F32 = 0, OUT_HEAD = 1, OUT_HEADT = 2 };

template <int OMODE>
DI void gemm_core(const short* __restrict__ A, const short* __restrict__ B,
                  void* __restrict__ Cp, float scale, int bm, int bn) {
  __shared__ __align__(16) short sA[128 * 64];
  __shared__ __align__(16) short sB[128 * 64];

  const int tid = threadIdx.x;
  const int lane = tid & 63;
  const int wid = tid >> 6;
  const int wm = wid >> 1, wn = wid & 1;
  const int l15 = lane & 15, lq = lane >> 4;
  const int lrr = lane >> 3;  // row within 8-row group
  const int lch = lane & 7;   // 16B chunk within 128B row

  f32x4 acc[4][4] = {};

  for (int k0 = 0; k0 < 1024; k0 += 64) {
#pragma unroll
    for (int i = 0; i < 4; ++i) {
      int r0 = wid * 32 + i * 8;
      int rr = r0 + lrr;
      int sc = (lch ^ (rr & 7)) << 3;  // inverse-swizzled source chunk (shorts)
      gl16(A + (size_t)(bm + rr) * 1024 + k0 + sc, sA + r0 * 64);
      gl16(B + (size_t)(bn + rr) * 1024 + k0 + sc, sB + r0 * 64);
    }
    __syncthreads();  // drains vmcnt before barrier

#pragma unroll
    for (int ks = 0; ks < 2; ++ks) {
      short8 a[4], b[4];
#pragma unroll
      for (int mt = 0; mt < 4; ++mt) {
        int row = wm * 64 + mt * 16 + l15;
        int off = (row * 128 + ks * 64 + lq * 16) ^ ((row & 7) << 4);
        a[mt] = *(const short8*)((const char*)sA + off);
      }
#pragma unroll
      for (int nt = 0; nt < 4; ++nt) {
        int row = wn * 64 + nt * 16 + l15;
        int off = (row * 128 + ks * 64 + lq * 16) ^ ((row & 7) << 4);
        b[nt] = *(const short8*)((const char*)sB + off);
      }
#pragma unroll
      for (int mt = 0; mt < 4; ++mt)
#pragma unroll
        for (int nt = 0; nt < 4; ++nt) {
          if (OMODE == OUT_HEADT)
            acc[mt][nt] = __builtin_amdgcn_mfma_f32_16x16x32_bf16(
                b[nt], a[mt], acc[mt][nt], 0, 0, 0);
          else
            acc[mt][nt] = __builtin_amdgcn_mfma_f32_16x16x32_bf16(
                a[mt], b[nt], acc[mt][nt], 0, 0, 0);
        }
    }
    __syncthreads();
  }

#pragma unroll
  for (int mt = 0; mt < 4; ++mt) {
#pragma unroll
    for (int nt = 0; nt < 4; ++nt) {
#pragma unroll
      for (int r = 0; r < 4; ++r) {
        float val = acc[mt][nt][r] * scale;
        if (OMODE == OUT_HEADT) {
          int f = bn + wn * 64 + nt * 16 + lq * 4 + r;
          int t = bm + wm * 64 + mt * 16 + l15;
          int bb = t >> 11, s = t & 2047;
          int h = f >> 6, dh = f & 63;
          ((short*)Cp)[((size_t)((bb * 16 + h) * 64 + dh)) * 2048 + s] = f2bf(val);
        } else {
          int rowg = bm + wm * 64 + mt * 16 + lq * 4 + r;
          int colg = bn + wn * 64 + nt * 16 + l15;
          if (OMODE == OUT_HEAD) {
            int bb = rowg >> 11, s = rowg & 2047;
            int h = colg >> 6, dh = colg & 63;
            ((short*)Cp)[((size_t)(bb * 16 + h) * 2048 + s) * 64 + dh] = f2bf(val);
          } else {
            ((float*)Cp)[(size_t)rowg * 1024 + colg] = val;
          }
        }
      }
    }
  }
}

// XCD-aware tile mapping: 8 n-tiles of one A row-panel run consecutively on
// ONE XCD (id&7 = xcd under round-robin dispatch) -> A panel stays in its L2.
DI void xcd_map(int id, int& bm, int& bn) {
  int xcd = id & 7, slot = id >> 3;
  int panel = xcd + 8 * (slot >> 3);
  int ntile = slot & 7;
  bm = panel * 128;
  bn = ntile * 128;
}

__global__ __launch_bounds__(256) void proj_gemm3(
    const short* __restrict__ qb, const short* __restrict__ kb,
    const short* __restrict__ vb, const short* __restrict__ wq,
    const short* __restrict__ wk, const short* __restrict__ wv,
    short* __restrict__ xq, short* __restrict__ xk, short* __restrict__ xvT) {
  int z = blockIdx.z;
  int bm, bn;
  xcd_map(blockIdx.x, bm, bn);
  if (z == 0) {
    gemm_core<OUT_HEAD>(qb, wq, xq, QSCALE, bm, bn);
  } else if (z == 1) {
    gemm_core<OUT_HEAD>(kb, wk, xk, 1.0f, bm, bn);
  } else {
    gemm_core<OUT_HEADT>(vb, wv, xvT, 1.0f, bm, bn);
  }
}

__global__ __launch_bounds__(256) void proj_oneN(
    const short* __restrict__ A, const short* __restrict__ B,
    short* __restrict__ C, float scale) {
  int bm, bn;
  xcd_map(blockIdx.x, bm, bn);
  gemm_core<OUT_HEAD>(A, B, C, scale, bm, bn);
}

__global__ __launch_bounds__(256) void proj_oneT(
    const short* __restrict__ A, const short* __restrict__ B,
    short* __restrict__ C, float scale) {
  int bm, bn;
  xcd_map(blockIdx.x, bm, bn);
  gemm_core<OUT_HEADT>(A, B, C, scale, bm, bn);
}

__global__ __launch_bounds__(256) void final_gemm(
    const short* __restrict__ oa, const short* __restrict__ wo,
    float* __restrict__ out) {
  int bm, bn;
  xcd_map(blockIdx.x, bm, bn);
  gemm_core<OUT_F32>(oa, wo, out, 1.0f, bm, bn);
}

// ---------------------------------------------------------------------------
// Causal flash attention, swapped-QK^T, exp2-domain softmax, defer-max.
// 512 threads = 8 waves; block owns a 128-row q-supertile; pairs (i, 15-i)
// -> 34 KV tiles per block, 512 blocks, zero imbalance.
// Double-buffered K/V^T LDS, ONE barrier per KV tile.
// Mask gate fix (R7 bug): per-element causal mask is needed whenever
// max_key (kv0+63) > qfirst (wave's FIRST q row), not qlast.
// LDS = 32KB (K,VT dbuf) + 16KB (P) = 48KB.
// ---------------------------------------------------------------------------
__global__ __launch_bounds__(512, 4) void attn_k(
    const short* __restrict__ Xq, const short* __restrict__ Xk,
    const short* __restrict__ XvT, short* __restrict__ Oa) {
  __shared__ __align__(16) short sK[2][64 * 64];
  __shared__ __align__(16) short sVT[2][64 * 64];
  __shared__ __align__(16) short sP[8][16 * 64];

  const int tid = threadIdx.x;
  const int lane = tid & 63;
  const int wid = tid >> 6;  // 0..7
  const int l15 = lane & 15, lq = lane >> 4;
  const int bid = blockIdx.x;
  const int ipair = bid >> 6;  // 0..7
  const int bh = bid & 63;     // same-bh blocks land on same XCD
  const int b = bh >> 4, h = bh & 15;

  const short* Q = Xq + (size_t)bh * 2048 * 64;
  const short* K = Xk + (size_t)bh * 2048 * 64;
  const short* VT = XvT + (size_t)bh * 64 * 2048;

  // staging: 512 threads x 16B covers one 64x64 bf16 tile (K and VT each)
  const int srow = tid >> 3;       // 0..63
  const int scol = (tid & 7) * 8;  // 0..56
  const int soff = (srow * 128 + scol * 2) ^ ((srow & 7) << 4);

  short8 kreg, vreg;
  kreg = *(const short8*)(K + (size_t)srow * 64 + scol);
  vreg = *(const short8*)(VT + (size_t)srow * 2048 + scol);

  // prologue: tile 0 -> buffer 0
  *(short8*)((char*)sK[0] + soff) = kreg;
  *(short8*)((char*)sVT[0] + soff) = vreg;

  short* sPw = sP[wid];
  int p = 0;

  for (int seg = 0; seg < 2; ++seg) {
    const int qt = seg ? ipair : (15 - ipair);  // long supertile first
    const int qfirst = qt * 128 + wid * 16;     // wave's first q row
    const int qg = qfirst + l15;                // this lane's q row
    const int qlast = qfirst + 15;              // wave's max q row
    const int ntile = 2 * qt + 2;

    short8 qf[2];
#pragma unroll
    for (int ks = 0; ks < 2; ++ks)
      qf[ks] = *(const short8*)(Q + (size_t)qg * 64 + ks * 32 + lq * 8);

    float m_run = -1e30f, l_run = 0.f;
    f32x4 acc[4] = {};  // O^T[dh = mt*16+lq*4+r][q = l15]

    for (int kt = 0; kt < ntile; ++kt) {
      const int kv0 = kt * 64;
      __syncthreads();  // buf[p] ready for all waves

      // ---- T14: issue next tile's global loads (land during compute) ----
      int nkt = kt + 1, nseg = seg;
      if (nkt >= ntile) { nseg = seg + 1; nkt = 0; }
      const bool hn = (nseg < 2);
      if (hn) {
        const int kn = nkt * 64;
        kreg = *(const short8*)(K + (size_t)(kn + srow) * 64 + scol);
        vreg = *(const short8*)(VT + (size_t)srow * 2048 + kn + scol);
      }

      // wave-uniform triage against this wave's q range
      const bool fullmask = (kv0 > qlast);
      if (!fullmask) {
        const bool needmask = (kv0 + 63 > qfirst);  // any key > any row
        const char* bufK = (const char*)sK[p];
        const char* bufV = (const char*)sVT[p];

        // ---- QK^T swapped: sc[nt][r] = S[key=kv0+nt*16+lq*4+r][q=l15] ----
        f32x4 sc[4] = {};
        __builtin_amdgcn_s_setprio(1);
#pragma unroll
        for (int ks = 0; ks < 2; ++ks) {
          short8 kf[4];
#pragma unroll
          for (int nt = 0; nt < 4; ++nt) {
            int row = nt * 16 + l15;
            int off = (row * 128 + ks * 64 + lq * 16) ^ ((row & 7) << 4);
            kf[nt] = *(const short8*)(bufK + off);
          }
#pragma unroll
          for (int nt = 0; nt < 4; ++nt)
            sc[nt] = __builtin_amdgcn_mfma_f32_16x16x32_bf16(kf[nt], qf[ks],
                                                             sc[nt], 0, 0, 0);
        }
        __builtin_amdgcn_s_setprio(0);

        // ---- mask (diag tiles only) + tile max ----
        float pv[4][4];
        float m = -1e30f;
        if (needmask) {
#pragma unroll
          for (int nt = 0; nt < 4; ++nt)
#pragma unroll
            for (int r = 0; r < 4; ++r) {
              float s = sc[nt][r];
              if (kv0 + nt * 16 + lq * 4 + r > qg) s = -1e30f;
              pv[nt][r] = s;
              m = fmaxf(m, s);
            }
        } else {
#pragma unroll
          for (int nt = 0; nt < 4; ++nt)
#pragma unroll
            for (int r = 0; r < 4; ++r) {
              float s = sc[nt][r];
              pv[nt][r] = s;
              m = fmaxf(m, s);
            }
        }
        m = fmaxf(m, __shfl_xor(m, 16));
        m = fmaxf(m, __shfl_xor(m, 32));

        // ---- T13 defer-max: rescale only when max grows past THR=8 ----
        if (!__all(m - m_run <= 8.0f)) {
          const float m_new = fmaxf(m_run, m);
          const float corr = fexp2(m_run - m_new);
          l_run *= corr;
#pragma unroll
          for (int mt = 0; mt < 4; ++mt)
#pragma unroll
            for (int r = 0; r < 4; ++r) acc[mt][r] *= corr;
          m_run = m_new;
        }

        float rsum = 0.f;
#pragma unroll
        for (int nt = 0; nt < 4; ++nt)
#pragma unroll
          for (int r = 0; r < 4; ++r) {
            float e = fexp2(pv[nt][r] - m_run);
            pv[nt][r] = e;
            rsum += e;
          }
        rsum += __shfl_xor(rsum, 16);
        rsum += __shfl_xor(rsum, 32);
        l_run += rsum;

        // ---- P -> per-wave LDS [q][key], vectorized ds_write_b64 ----
#pragma unroll
        for (int nt = 0; nt < 4; ++nt) {
          short4v pw;
#pragma unroll
          for (int r = 0; r < 4; ++r) pw[r] = f2bf(pv[nt][r]);
          int off = (l15 * 128 + nt * 32 + lq * 8) ^ ((l15 & 7) << 4);
          *(short4v*)((char*)sPw + off) = pw;
        }

        // ---- PV: O^T[dh][q] += V^T[dh][key] * P^T[key][q] ----
        __builtin_amdgcn_s_setprio(1);
#pragma unroll
        for (int ks = 0; ks < 2; ++ks) {
          int poff = (l15 * 128 + ks * 64 + lq * 16) ^ ((l15 & 7) << 4);
          short8 pf = *(const short8*)((const char*)sPw + poff);
#pragma unroll
          for (int mt = 0; mt < 4; ++mt) {
            int row = mt * 16 + l15;
            int voff = (row * 128 + ks * 64 + lq * 16) ^ ((row & 7) << 4);
            short8 vf = *(const short8*)(bufV + voff);
            acc[mt] = __builtin_amdgcn_mfma_f32_16x16x32_bf16(vf, pf, acc[mt],
                                                              0, 0, 0);
          }
        }
        __builtin_amdgcn_s_setprio(0);
      }

      // ---- write next tile into buf[p^1] (published by next barrier) ----
      if (hn) {
        *(short8*)((char*)sK[p ^ 1] + soff) = kreg;
        *(short8*)((char*)sVT[p ^ 1] + soff) = vreg;
      }
      p ^= 1;
    }

    // ---- epilogue: O[q][dh] = acc^T / l, packed 8B stores ----
    const float rl = 1.0f / l_run;
    short* orow = Oa + ((size_t)(b * 2048 + qg)) * 1024 + h * 64;
#pragma unroll
    for (int mt = 0; mt < 4; ++mt) {
      short4v o;
#pragma unroll
      for (int r = 0; r < 4; ++r) o[r] = f2bf(acc[mt][r] * rl);
      *(short4v*)(orow + mt * 16 + lq * 4) = o;
    }
  }
}

// ---------------------------------------------------------------------------
extern "C" void kernel_launch(void* const* d_in, const int* in_sizes, int n_in,
                              void* d_out, int out_size, void* d_ws,
                              size_t ws_size, hipStream_t stream) {
  const float* q = (const float*)d_in[0];
  const float* k = (const float*)d_in[1];
  const float* v = (const float*)d_in[2];
  const float* Wq = (const float*)d_in[3];
  const float* Wk = (const float*)d_in[4];
  const float* Wv = (const float*)d_in[5];
  const float* Wo = (const float*)d_in[6];

  char* ws = (char*)d_ws;
  short* wq_b = (short*)(ws + (0ull << 20));
  short* wk_b = (short*)(ws + (2ull << 20));
  short* wv_b = (short*)(ws + (4ull << 20));
  short* wo_b = (short*)(ws + (6ull << 20));
  short* xq  = (short*)(ws + (8ull << 20));    // 16 MB each, [B,H,S,Dh] bf16
  short* xk  = (short*)(ws + (24ull << 20));
  short* xvT = (short*)(ws + (56ull << 20));   // [B,H,Dh,S] bf16

  convert_w<<<dim3(1024, 1, 4), 256, 0, stream>>>(Wq, Wk, Wv, Wo, wq_b);

  if (ws_size >= (122ull << 20)) {
    short* qb = (short*)(ws + (72ull << 20));  // 16 MB each, [B*S, D] bf16
    short* kb = (short*)(ws + (88ull << 20));
    short* vb = (short*)(ws + (104ull << 20));
    short* oa = qb;  // qb dead after proj_gemm3

    convert_x<<<dim3(4096, 1, 3), 256, 0, stream>>>(q, k, v, qb, kb, vb);
    proj_gemm3<<<dim3(512, 1, 3), 256, 0, stream>>>(qb, kb, vb, wq_b, wk_b,
                                                    wv_b, xq, xk, xvT);
    attn_k<<<dim3(512), 512, 0, stream>>>(xq, xk, xvT, oa);
    final_gemm<<<dim3(512), 256, 0, stream>>>(oa, wo_b, (float*)d_out);
  } else {
    // ping-pong fallback: one 16 MB staging buffer, sequential per-z
    short* X = (short*)(ws + (8ull << 20));
    short* xq2 = (short*)(ws + (24ull << 20));
    short* xk2 = (short*)(ws + (40ull << 20));
    short* xvT2 = (short*)(ws + (56ull << 20));
    short* oa2 = (short*)(ws + (72ull << 20));

    convert_one<<<dim3(4096), 256, 0, stream>>>(q, X);
    proj_oneN<<<dim3(512), 256, 0, stream>>>(X, wq_b, xq2, QSCALE);
    convert_one<<<dim3(4096), 256, 0, stream>>>(k, X);
    proj_oneN<<<dim3(512), 256, 0, stream>>>(X, wk_b, xk2, 1.0f);
    convert_one<<<dim3(4096), 256, 0, stream>>>(v, X);
    proj_oneT<<<dim3(512), 256, 0, stream>>>(X, wv_b, xvT2, 1.0f);
    attn_k<<<dim3(512), 512, 0, stream>>>(xq2, xk2, xvT2, oa2);
    final_gemm<<<dim3(512), 256, 0, stream>>>(oa2, wo_b, (float*)d_out);
  }
}

// Round 9
// 177.140 us; speedup vs baseline: 2.6150x; 1.0058x over previous
//
#include <hip/hip_runtime.h>
#include <hip/hip_bf16.h>

#define DI __device__ __forceinline__

typedef __attribute__((ext_vector_type(8))) short short8;
typedef __attribute__((ext_vector_type(4))) short short4v;
typedef __attribute__((ext_vector_type(4))) float f32x4;

// Q pre-scale: 1/sqrt(64) * log2(e)  (exp2-domain softmax)
#define QSCALE 0.180336885f

// RNE float -> bf16 via native fptrunc (compiler packs v_cvt_pk_bf16_f32)
DI short f2bf(float f) {
  __hip_bfloat16 h = __float2bfloat16(f);
  return __builtin_bit_cast(short, h);
}

DI float fexp2(float x) {
#if __has_builtin(__builtin_amdgcn_exp2f)
  return __builtin_amdgcn_exp2f(x);
#else
  return exp2f(x);
#endif
}

// async global->LDS, 16B per lane. LDS dest = wave-uniform base + lane*16.
DI void gl16(const short* g, short* l) {
  __builtin_amdgcn_global_load_lds(
      (const __attribute__((address_space(1))) void*)g,
      (__attribute__((address_space(3))) void*)l, 16, 0, 0);
}

// ---------------------------------------------------------------------------
// Weight conversion: 4 x [1024x1024] fp32 -> bf16 (contiguous in ws)
// ---------------------------------------------------------------------------
__global__ __launch_bounds__(256) void convert_w(
    const float* __restrict__ wq, const float* __restrict__ wk,
    const float* __restrict__ wv, const float* __restrict__ wo,
    short* __restrict__ dst) {
  int z = blockIdx.z;
  const float* src = (z == 0) ? wq : (z == 1) ? wk : (z == 2) ? wv : wo;
  short* d = dst + (size_t)z * 1024 * 1024;
  int i = (blockIdx.x * 256 + threadIdx.x) * 4;
  float4 f = *(const float4*)(src + i);
  short4v v;
  v[0] = f2bf(f.x); v[1] = f2bf(f.y); v[2] = f2bf(f.z); v[3] = f2bf(f.w);
  *(short4v*)(d + i) = v;
}

// q/k/v fp32 -> bf16, all three in one launch (grid.z selects)
__global__ __launch_bounds__(256) void convert_x(
    const float* __restrict__ q, const float* __restrict__ k,
    const float* __restrict__ v, short* __restrict__ qb,
    short* __restrict__ kb, short* __restrict__ vb) {
  int z = blockIdx.z;
  const float* src = (z == 0) ? q : (z == 1) ? k : v;
  short* dst = (z == 0) ? qb : (z == 1) ? kb : vb;
  size_t i = ((size_t)blockIdx.x * 256 + threadIdx.x) * 8;
  float4 f0 = *(const float4*)(src + i);
  float4 f1 = *(const float4*)(src + i + 4);
  short8 o;
  o[0] = f2bf(f0.x); o[1] = f2bf(f0.y); o[2] = f2bf(f0.z); o[3] = f2bf(f0.w);
  o[4] = f2bf(f1.x); o[5] = f2bf(f1.y); o[6] = f2bf(f1.z); o[7] = f2bf(f1.w);
  *(short8*)(dst + i) = o;
}

// single src->dst convert (fallback path)
__global__ __launch_bounds__(256) void convert_one(
    const float* __restrict__ src, short* __restrict__ dst) {
  size_t i = ((size_t)blockIdx.x * 256 + threadIdx.x) * 8;
  float4 f0 = *(const float4*)(src + i);
  float4 f1 = *(const float4*)(src + i + 4);
  short8 o;
  o[0] = f2bf(f0.x); o[1] = f2bf(f0.y); o[2] = f2bf(f0.z); o[3] = f2bf(f0.w);
  o[4] = f2bf(f1.x); o[5] = f2bf(f1.y); o[6] = f2bf(f1.z); o[7] = f2bf(f1.w);
  *(short8*)(dst + i) = o;
}

// ---------------------------------------------------------------------------
// bf16 GEMM core: C[m][n] = sum_k A[m][k]*B[n][k].  A [8192][1024], B [1024][1024].
// 128x128 tile, BK=64, 4 waves x (64x64). global_load_lds width=16 staging,
// inverse-swizzled global source + linear LDS dest + XOR-swizzled ds_read.
// LDS buffers are passed in from the kernel (declared ONCE per kernel) so
// multi-instantiation kernels don't multiply the LDS reservation (R8 bug:
// proj_gemm3 reserved 64KB for two instantiations -> occupancy halved).
// OMODE: 0 = fp32 row-major; 1 = bf16 [B,H,S,Dh]; 2 = bf16 [B,H,Dh,S]
// ---------------------------------------------------------------------------
enum { OUT_F32 = 0, OUT_HEAD = 1, OUT_HEADT = 2 };

template <int OMODE>
DI void gemm_core(short* sA, short* sB, const short* __restrict__ A,
                  const short* __restrict__ B, void* __restrict__ Cp,
                  float scale, int bm, int bn) {
  const int tid = threadIdx.x;
  const int lane = tid & 63;
  const int wid = tid >> 6;
  const int wm = wid >> 1, wn = wid & 1;
  const int l15 = lane & 15, lq = lane >> 4;
  const int lrr = lane >> 3;  // row within 8-row group
  const int lch = lane & 7;   // 16B chunk within 128B row

  f32x4 acc[4][4] = {};

  for (int k0 = 0; k0 < 1024; k0 += 64) {
#pragma unroll
    for (int i = 0; i < 4; ++i) {
      int r0 = wid * 32 + i * 8;
      int rr = r0 + lrr;
      int sc = (lch ^ (rr & 7)) << 3;  // inverse-swizzled source chunk (shorts)
      gl16(A + (size_t)(bm + rr) * 1024 + k0 + sc, sA + r0 * 64);
      gl16(B + (size_t)(bn + rr) * 1024 + k0 + sc, sB + r0 * 64);
    }
    __syncthreads();  // drains vmcnt before barrier

#pragma unroll
    for (int ks = 0; ks < 2; ++ks) {
      short8 a[4], b[4];
#pragma unroll
      for (int mt = 0; mt < 4; ++mt) {
        int row = wm * 64 + mt * 16 + l15;
        int off = (row * 128 + ks * 64 + lq * 16) ^ ((row & 7) << 4);
        a[mt] = *(const short8*)((const char*)sA + off);
      }
#pragma unroll
      for (int nt = 0; nt < 4; ++nt) {
        int row = wn * 64 + nt * 16 + l15;
        int off = (row * 128 + ks * 64 + lq * 16) ^ ((row & 7) << 4);
        b[nt] = *(const short8*)((const char*)sB + off);
      }
#pragma unroll
      for (int mt = 0; mt < 4; ++mt)
#pragma unroll
        for (int nt = 0; nt < 4; ++nt) {
          if (OMODE == OUT_HEADT)
            acc[mt][nt] = __builtin_amdgcn_mfma_f32_16x16x32_bf16(
                b[nt], a[mt], acc[mt][nt], 0, 0, 0);
          else
            acc[mt][nt] = __builtin_amdgcn_mfma_f32_16x16x32_bf16(
                a[mt], b[nt], acc[mt][nt], 0, 0, 0);
        }
    }
    __syncthreads();
  }

#pragma unroll
  for (int mt = 0; mt < 4; ++mt) {
#pragma unroll
    for (int nt = 0; nt < 4; ++nt) {
#pragma unroll
      for (int r = 0; r < 4; ++r) {
        float val = acc[mt][nt][r] * scale;
        if (OMODE == OUT_HEADT) {
          int f = bn + wn * 64 + nt * 16 + lq * 4 + r;
          int t = bm + wm * 64 + mt * 16 + l15;
          int bb = t >> 11, s = t & 2047;
          int h = f >> 6, dh = f & 63;
          ((short*)Cp)[((size_t)((bb * 16 + h) * 64 + dh)) * 2048 + s] = f2bf(val);
        } else {
          int rowg = bm + wm * 64 + mt * 16 + lq * 4 + r;
          int colg = bn + wn * 64 + nt * 16 + l15;
          if (OMODE == OUT_HEAD) {
            int bb = rowg >> 11, s = rowg & 2047;
            int h = colg >> 6, dh = colg & 63;
            ((short*)Cp)[((size_t)(bb * 16 + h) * 2048 + s) * 64 + dh] = f2bf(val);
          } else {
            ((float*)Cp)[(size_t)rowg * 1024 + colg] = val;
          }
        }
      }
    }
  }
}

// XCD-aware tile mapping: 8 n-tiles of one A row-panel run consecutively on
// ONE XCD (id&7 = xcd under round-robin dispatch) -> A panel stays in its L2.
DI void xcd_map(int id, int& bm, int& bn) {
  int xcd = id & 7, slot = id >> 3;
  int panel = xcd + 8 * (slot >> 3);
  int ntile = slot & 7;
  bm = panel * 128;
  bn = ntile * 128;
}

#define GEMM_LDS()                              \
  __shared__ __align__(16) short sA[128 * 64];  \
  __shared__ __align__(16) short sB[128 * 64];

__global__ __launch_bounds__(256) void proj_gemm3(
    const short* __restrict__ qb, const short* __restrict__ kb,
    const short* __restrict__ vb, const short* __restrict__ wq,
    const short* __restrict__ wk, const short* __restrict__ wv,
    short* __restrict__ xq, short* __restrict__ xk, short* __restrict__ xvT) {
  GEMM_LDS();
  int z = blockIdx.z;
  int bm, bn;
  xcd_map(blockIdx.x, bm, bn);
  if (z == 0) {
    gemm_core<OUT_HEAD>(sA, sB, qb, wq, xq, QSCALE, bm, bn);
  } else if (z == 1) {
    gemm_core<OUT_HEAD>(sA, sB, kb, wk, xk, 1.0f, bm, bn);
  } else {
    gemm_core<OUT_HEADT>(sA, sB, vb, wv, xvT, 1.0f, bm, bn);
  }
}

__global__ __launch_bounds__(256) void proj_oneN(
    const short* __restrict__ A, const short* __restrict__ B,
    short* __restrict__ C, float scale) {
  GEMM_LDS();
  int bm, bn;
  xcd_map(blockIdx.x, bm, bn);
  gemm_core<OUT_HEAD>(sA, sB, A, B, C, scale, bm, bn);
}

__global__ __launch_bounds__(256) void proj_oneT(
    const short* __restrict__ A, const short* __restrict__ B,
    short* __restrict__ C, float scale) {
  GEMM_LDS();
  int bm, bn;
  xcd_map(blockIdx.x, bm, bn);
  gemm_core<OUT_HEADT>(sA, sB, A, B, C, scale, bm, bn);
}

__global__ __launch_bounds__(256) void final_gemm(
    const short* __restrict__ oa, const short* __restrict__ wo,
    float* __restrict__ out) {
  GEMM_LDS();
  int bm, bn;
  xcd_map(blockIdx.x, bm, bn);
  gemm_core<OUT_F32>(sA, sB, oa, wo, out, 1.0f, bm, bn);
}

// ---------------------------------------------------------------------------
// Causal flash attention, swapped-QK^T, exp2-domain softmax, defer-max.
// 512 threads = 8 waves; block owns a 128-row q-supertile; pairs (i, 15-i)
// -> 34 KV tiles per block, 512 blocks, zero imbalance.
// Double-buffered K/V^T LDS, ONE barrier per KV tile.
// LDS = 32KB (K,VT dbuf) + 16KB (P) = 48KB.
// ---------------------------------------------------------------------------
__global__ __launch_bounds__(512, 4) void attn_k(
    const short* __restrict__ Xq, const short* __restrict__ Xk,
    const short* __restrict__ XvT, short* __restrict__ Oa) {
  __shared__ __align__(16) short sK[2][64 * 64];
  __shared__ __align__(16) short sVT[2][64 * 64];
  __shared__ __align__(16) short sP[8][16 * 64];

  const int tid = threadIdx.x;
  const int lane = tid & 63;
  const int wid = tid >> 6;  // 0..7
  const int l15 = lane & 15, lq = lane >> 4;
  const int bid = blockIdx.x;
  const int ipair = bid >> 6;  // 0..7
  const int bh = bid & 63;     // same-bh blocks land on same XCD
  const int b = bh >> 4, h = bh & 15;

  const short* Q = Xq + (size_t)bh * 2048 * 64;
  const short* K = Xk + (size_t)bh * 2048 * 64;
  const short* VT = XvT + (size_t)bh * 64 * 2048;

  // staging: 512 threads x 16B covers one 64x64 bf16 tile (K and VT each)
  const int srow = tid >> 3;       // 0..63
  const int scol = (tid & 7) * 8;  // 0..56
  const int soff = (srow * 128 + scol * 2) ^ ((srow & 7) << 4);

  short8 kreg, vreg;
  kreg = *(const short8*)(K + (size_t)srow * 64 + scol);
  vreg = *(const short8*)(VT + (size_t)srow * 2048 + scol);

  // prologue: tile 0 -> buffer 0
  *(short8*)((char*)sK[0] + soff) = kreg;
  *(short8*)((char*)sVT[0] + soff) = vreg;

  short* sPw = sP[wid];
  int p = 0;

  for (int seg = 0; seg < 2; ++seg) {
    const int qt = seg ? ipair : (15 - ipair);  // long supertile first
    const int qfirst = qt * 128 + wid * 16;     // wave's first q row
    const int qg = qfirst + l15;                // this lane's q row
    const int qlast = qfirst + 15;              // wave's max q row
    const int ntile = 2 * qt + 2;

    short8 qf[2];
#pragma unroll
    for (int ks = 0; ks < 2; ++ks)
      qf[ks] = *(const short8*)(Q + (size_t)qg * 64 + ks * 32 + lq * 8);

    float m_run = -1e30f, l_run = 0.f;
    f32x4 acc[4] = {};  // O^T[dh = mt*16+lq*4+r][q = l15]

    for (int kt = 0; kt < ntile; ++kt) {
      const int kv0 = kt * 64;
      __syncthreads();  // buf[p] ready for all waves

      // ---- T14: issue next tile's global loads (land during compute) ----
      int nkt = kt + 1, nseg = seg;
      if (nkt >= ntile) { nseg = seg + 1; nkt = 0; }
      const bool hn = (nseg < 2);
      if (hn) {
        const int kn = nkt * 64;
        kreg = *(const short8*)(K + (size_t)(kn + srow) * 64 + scol);
        vreg = *(const short8*)(VT + (size_t)srow * 2048 + kn + scol);
      }

      // wave-uniform triage against this wave's q range
      const bool fullmask = (kv0 > qlast);
      if (!fullmask) {
        const bool needmask = (kv0 + 63 > qfirst);  // any key > any row
        const char* bufK = (const char*)sK[p];
        const char* bufV = (const char*)sVT[p];

        // ---- QK^T swapped: sc[nt][r] = S[key=kv0+nt*16+lq*4+r][q=l15] ----
        f32x4 sc[4] = {};
        __builtin_amdgcn_s_setprio(1);
#pragma unroll
        for (int ks = 0; ks < 2; ++ks) {
          short8 kf[4];
#pragma unroll
          for (int nt = 0; nt < 4; ++nt) {
            int row = nt * 16 + l15;
            int off = (row * 128 + ks * 64 + lq * 16) ^ ((row & 7) << 4);
            kf[nt] = *(const short8*)(bufK + off);
          }
#pragma unroll
          for (int nt = 0; nt < 4; ++nt)
            sc[nt] = __builtin_amdgcn_mfma_f32_16x16x32_bf16(kf[nt], qf[ks],
                                                             sc[nt], 0, 0, 0);
        }
        __builtin_amdgcn_s_setprio(0);

        // ---- mask (diag tiles only) + tile max ----
        float pv[4][4];
        float m = -1e30f;
        if (needmask) {
#pragma unroll
          for (int nt = 0; nt < 4; ++nt)
#pragma unroll
            for (int r = 0; r < 4; ++r) {
              float s = sc[nt][r];
              if (kv0 + nt * 16 + lq * 4 + r > qg) s = -1e30f;
              pv[nt][r] = s;
              m = fmaxf(m, s);
            }
        } else {
#pragma unroll
          for (int nt = 0; nt < 4; ++nt)
#pragma unroll
            for (int r = 0; r < 4; ++r) {
              float s = sc[nt][r];
              pv[nt][r] = s;
              m = fmaxf(m, s);
            }
        }
        m = fmaxf(m, __shfl_xor(m, 16));
        m = fmaxf(m, __shfl_xor(m, 32));

        // ---- T13 defer-max: rescale only when max grows past THR=8 ----
        if (!__all(m - m_run <= 8.0f)) {
          const float m_new = fmaxf(m_run, m);
          const float corr = fexp2(m_run - m_new);
          l_run *= corr;
#pragma unroll
          for (int mt = 0; mt < 4; ++mt)
#pragma unroll
            for (int r = 0; r < 4; ++r) acc[mt][r] *= corr;
          m_run = m_new;
        }

        float rsum = 0.f;
#pragma unroll
        for (int nt = 0; nt < 4; ++nt)
#pragma unroll
          for (int r = 0; r < 4; ++r) {
            float e = fexp2(pv[nt][r] - m_run);
            pv[nt][r] = e;
            rsum += e;
          }
        rsum += __shfl_xor(rsum, 16);
        rsum += __shfl_xor(rsum, 32);
        l_run += rsum;

        // ---- P -> per-wave LDS [q][key], vectorized ds_write_b64 ----
#pragma unroll
        for (int nt = 0; nt < 4; ++nt) {
          short4v pw;
#pragma unroll
          for (int r = 0; r < 4; ++r) pw[r] = f2bf(pv[nt][r]);
          int off = (l15 * 128 + nt * 32 + lq * 8) ^ ((l15 & 7) << 4);
          *(short4v*)((char*)sPw + off) = pw;
        }

        // ---- PV: O^T[dh][q] += V^T[dh][key] * P^T[key][q] ----
        __builtin_amdgcn_s_setprio(1);
#pragma unroll
        for (int ks = 0; ks < 2; ++ks) {
          int poff = (l15 * 128 + ks * 64 + lq * 16) ^ ((l15 & 7) << 4);
          short8 pf = *(const short8*)((const char*)sPw + poff);
#pragma unroll
          for (int mt = 0; mt < 4; ++mt) {
            int row = mt * 16 + l15;
            int voff = (row * 128 + ks * 64 + lq * 16) ^ ((row & 7) << 4);
            short8 vf = *(const short8*)(bufV + voff);
            acc[mt] = __builtin_amdgcn_mfma_f32_16x16x32_bf16(vf, pf, acc[mt],
                                                              0, 0, 0);
          }
        }
        __builtin_amdgcn_s_setprio(0);
      }

      // ---- write next tile into buf[p^1] (published by next barrier) ----
      if (hn) {
        *(short8*)((char*)sK[p ^ 1] + soff) = kreg;
        *(short8*)((char*)sVT[p ^ 1] + soff) = vreg;
      }
      p ^= 1;
    }

    // ---- epilogue: O[q][dh] = acc^T / l, packed 8B stores ----
    const float rl = 1.0f / l_run;
    short* orow = Oa + ((size_t)(b * 2048 + qg)) * 1024 + h * 64;
#pragma unroll
    for (int mt = 0; mt < 4; ++mt) {
      short4v o;
#pragma unroll
      for (int r = 0; r < 4; ++r) o[r] = f2bf(acc[mt][r] * rl);
      *(short4v*)(orow + mt * 16 + lq * 4) = o;
    }
  }
}

// ---------------------------------------------------------------------------
extern "C" void kernel_launch(void* const* d_in, const int* in_sizes, int n_in,
                              void* d_out, int out_size, void* d_ws,
                              size_t ws_size, hipStream_t stream) {
  const float* q = (const float*)d_in[0];
  const float* k = (const float*)d_in[1];
  const float* v = (const float*)d_in[2];
  const float* Wq = (const float*)d_in[3];
  const float* Wk = (const float*)d_in[4];
  const float* Wv = (const float*)d_in[5];
  const float* Wo = (const float*)d_in[6];

  char* ws = (char*)d_ws;
  short* wq_b = (short*)(ws + (0ull << 20));
  short* wk_b = (short*)(ws + (2ull << 20));
  short* wv_b = (short*)(ws + (4ull << 20));
  short* wo_b = (short*)(ws + (6ull << 20));
  short* xq  = (short*)(ws + (8ull << 20));    // 16 MB each, [B,H,S,Dh] bf16
  short* xk  = (short*)(ws + (24ull << 20));
  short* xvT = (short*)(ws + (56ull << 20));   // [B,H,Dh,S] bf16

  convert_w<<<dim3(1024, 1, 4), 256, 0, stream>>>(Wq, Wk, Wv, Wo, wq_b);

  if (ws_size >= (122ull << 20)) {
    short* qb = (short*)(ws + (72ull << 20));  // 16 MB each, [B*S, D] bf16
    short* kb = (short*)(ws + (88ull << 20));
    short* vb = (short*)(ws + (104ull << 20));
    short* oa = qb;  // qb dead after proj_gemm3

    convert_x<<<dim3(4096, 1, 3), 256, 0, stream>>>(q, k, v, qb, kb, vb);
    proj_gemm3<<<dim3(512, 1, 3), 256, 0, stream>>>(qb, kb, vb, wq_b, wk_b,
                                                    wv_b, xq, xk, xvT);
    attn_k<<<dim3(512), 512, 0, stream>>>(xq, xk, xvT, oa);
    final_gemm<<<dim3(512), 256, 0, stream>>>(oa, wo_b, (float*)d_out);
  } else {
    // ping-pong fallback: one 16 MB staging buffer, sequential per-z
    short* X = (short*)(ws + (8ull << 20));
    short* xq2 = (short*)(ws + (24ull << 20));
    short* xk2 = (short*)(ws + (40ull << 20));
    short* xvT2 = (short*)(ws + (56ull << 20));
    short* oa2 = (short*)(ws + (72ull << 20));

    convert_one<<<dim3(4096), 256, 0, stream>>>(q, X);
    proj_oneN<<<dim3(512), 256, 0, stream>>>(X, wq_b, xq2, QSCALE);
    convert_one<<<dim3(4096), 256, 0, stream>>>(k, X);
    proj_oneN<<<dim3(512), 256, 0, stream>>>(X, wk_b, xk2, 1.0f);
    convert_one<<<dim3(4096), 256, 0, stream>>>(v, X);
    proj_oneT<<<dim3(512), 256, 0, stream>>>(X, wv_b, xvT2, 1.0f);
    attn_k<<<dim3(512), 512, 0, stream>>>(xq2, xk2, xvT2, oa2);
    final_gemm<<<dim3(512), 256, 0, stream>>>(oa2, wo_b, (float*)d_out);
  }
}